// Round 1
// baseline (32647.382 us; speedup 1.0000x reference)
//
#include <hip/hip_runtime.h>

// ---------------------------------------------------------------------------
// SSA (spiking self-attention) forward, eval mode.
// T=4, B=16, C=768, H=W=16, N=256, heads=8, dh=96.
// Pipeline: head_lif -> {conv+BN+LIF}x3 (q,k,v) -> kv=popcount(k&v) ->
//           o=q@kv*0.125 -> attn_lif(0.5) -> conv+BN (p) -> f32 out.
// All spike tensors stored as u8 {0,1} in ws. LIF state lives in registers
// across the T loop (kernels own all T for their (b, elem) slice).
// ---------------------------------------------------------------------------

#define BCN (16*768*256)          // elements per t-plane: 3,145,728
static const size_t SP = (size_t)4*16*768*256;  // spike tensor bytes: 12,582,912

// ---------------- BN affine precompute: scale/bias per channel --------------
__global__ __launch_bounds__(256) void bn_prep(
    const float* __restrict__ g, const float* __restrict__ be,
    const float* __restrict__ m, const float* __restrict__ va,
    float* __restrict__ out)   // out[0..767]=scale, out[768..1535]=bias
{
    int i = blockIdx.x*256 + threadIdx.x;
    if (i < 768){
        float s = g[i] / sqrtf(va[i] + 1e-5f);
        out[i] = s;
        out[768+i] = be[i] - m[i]*s;
    }
}

// ---------------- head LIF: x (f32) -> xs spikes (u8) ----------------------
__global__ __launch_bounds__(256) void head_lif(
    const float* __restrict__ x, unsigned char* __restrict__ xs)
{
    int i = blockIdx.x*256 + threadIdx.x;   // over B*C*N
    float v = 0.f;
    #pragma unroll
    for (int t=0;t<4;++t){
        float xv = x[(size_t)t*BCN + i];
        // h = v + (x - v)/2, in reference op order (all steps exact-roundable)
        float hh = __fadd_rn(v, __fmul_rn(__fsub_rn(xv, v), 0.5f));
        unsigned char s = (hh >= 1.0f) ? 1 : 0;
        v = s ? 0.f : hh;
        xs[(size_t)t*BCN + i] = s;
    }
}

// ---------------- dense conv3x3 + BN (+ optional LIF) ----------------------
// Block: 256 threads = one 16x16 image tile; 32 output channels per block.
// DO_LIF: grid (24 co-tiles, 16 b), loops t=0..3 with LIF state in regs.
// !DO_LIF: grid (24, 64 imgs), single pass, writes f32 to out_f32.
template<bool DO_LIF>
__global__ __launch_bounds__(256) void conv_bn_k(
    const unsigned char* __restrict__ in_spk,
    const float* __restrict__ w,            // [768][768][3][3]
    const float* __restrict__ sb,           // [0..767]=scale,[768..1535]=bias
    unsigned char* __restrict__ out_spk,
    float* __restrict__ out_f32)
{
    const int tid = threadIdx.x;
    const int co0 = blockIdx.x * 32;
    __shared__ float s_tile[8][18][18];
    __shared__ float w_tile[32][8][9];
    __shared__ unsigned int flags[8];
    const int y = tid >> 4, x = tid & 15;

    float vmem[32];
    #pragma unroll
    for (int i=0;i<32;++i) vmem[i]=0.f;

    const int NT = DO_LIF ? 4 : 1;
    for (int ti=0; ti<NT; ++ti){
        const int img = DO_LIF ? (ti*16 + blockIdx.y) : blockIdx.y;
        const unsigned char* ip = in_spk + (size_t)img*768*256;
        float acc[32];
        #pragma unroll
        for (int i=0;i<32;++i) acc[i]=0.f;

        for (int c0=0;c0<768;c0+=8){
            __syncthreads();                       // protect LDS reuse
            if (tid < 8) flags[tid] = 0u;
            __syncthreads();
            // stage 8 input channels, 18x18 zero-padded, u8 -> f32
            for (int idx=tid; idx<8*324; idx+=256){
                const int c_r = idx/324, rem = idx - c_r*324;
                const int ry = rem/18, rx = rem - ry*18;
                const int yy = ry-1, xx = rx-1;
                float v = 0.f;
                if ((unsigned)yy < 16u && (unsigned)xx < 16u){
                    v = (float)ip[(size_t)(c0+c_r)*256 + yy*16 + xx];
                    if (v != 0.f) atomicOr(&flags[c_r], 1u);
                }
                s_tile[c_r][ry][rx] = v;
            }
            __syncthreads();
            unsigned int anyf = flags[0]|flags[1]|flags[2]|flags[3]
                              | flags[4]|flags[5]|flags[6]|flags[7];
            if (anyf){
                // stage weights [32co][8c][9]
                for (int idx=tid; idx<32*72; idx+=256){
                    const int co_r = idx/72, rem = idx - co_r*72;
                    w_tile[co_r][rem/9][rem - (rem/9)*9] =
                        w[(size_t)(co0+co_r)*6912 + (size_t)c0*9 + rem];
                }
            }
            __syncthreads();
            if (!anyf) continue;                   // uniform: empty chunk
            #pragma unroll 1
            for (int c_r=0;c_r<8;++c_r){
                if (flags[c_r]==0u) continue;      // uniform per-channel skip
                float s9[9];
                #pragma unroll
                for (int dy=0;dy<3;++dy)
                    #pragma unroll
                    for (int dx=0;dx<3;++dx)
                        s9[dy*3+dx] = s_tile[c_r][y+dy][x+dx];
                #pragma unroll
                for (int co=0;co<32;++co){
                    float a = acc[co];
                    #pragma unroll
                    for (int k=0;k<9;++k) a += s9[k]*w_tile[co][c_r][k];
                    acc[co] = a;
                }
            }
        }
        // epilogue: BN affine (+ LIF)
        #pragma unroll
        for (int co=0;co<32;++co){
            const float sc = sb[co0+co], bi = sb[768+co0+co];
            const float yv = __fadd_rn(__fmul_rn(acc[co], sc), bi);
            if constexpr (DO_LIF){
                float hh = __fadd_rn(vmem[co], __fmul_rn(__fsub_rn(yv, vmem[co]), 0.5f));
                unsigned char s = (hh >= 1.0f) ? 1 : 0;
                vmem[co] = s ? 0.f : hh;
                out_spk[((size_t)img*768 + co0+co)*256 + tid] = s;
            } else {
                out_f32[((size_t)img*768 + co0+co)*256 + tid] = yv;
            }
        }
    }
}

// ---------------- fused attention: kv popcount + o + attn LIF --------------
// Block per (b, head): 512 threads = (n in 0..255) x (e-half in 0..1).
// kv[d][e] = popc(k_bits[d] & v_bits[e]) (exact ints);
// o[e][n] = 0.125 * sum_d q[d][n]*kv[d][e]; LIF(th=0.5) over t in regs.
__global__ __launch_bounds__(512) void attn_fused(
    const unsigned char* __restrict__ qs, const unsigned char* __restrict__ ks,
    const unsigned char* __restrict__ vs, unsigned char* __restrict__ os)
{
    const int tid = threadIdx.x;
    const int n = tid & 255, eh = tid >> 8;
    const int b = blockIdx.x, h = blockIdx.y;
    __shared__ unsigned int kb[96][9], vb[96][9];   // pad 9 to dodge conflicts
    __shared__ float kvl[96][96];
    float vmem[48];
    #pragma unroll
    for (int e=0;e<48;++e) vmem[e]=0.f;

    for (int t=0;t<4;++t){
        const size_t base = ((size_t)((t*16+b)*768 + h*96))*256;
        // build k/v bitmasks over n (256 bits = 8 words per d)
        for (int i=tid;i<768;i+=512){
            const int d=i>>3, wi=i&7;
            const unsigned int* kp=(const unsigned int*)(ks+base+(size_t)d*256+wi*32);
            const unsigned int* vp=(const unsigned int*)(vs+base+(size_t)d*256+wi*32);
            unsigned int kbits=0, vbits=0;
            #pragma unroll
            for (int jj=0;jj<8;++jj){
                const unsigned int kw=kp[jj], vw=vp[jj];
                kbits |= (kw&1u)<<(jj*4) | ((kw>>8)&1u)<<(jj*4+1)
                       | ((kw>>16)&1u)<<(jj*4+2) | ((kw>>24)&1u)<<(jj*4+3);
                vbits |= (vw&1u)<<(jj*4) | ((vw>>8)&1u)<<(jj*4+1)
                       | ((vw>>16)&1u)<<(jj*4+2) | ((vw>>24)&1u)<<(jj*4+3);
            }
            kb[d][wi]=kbits; vb[d][wi]=vbits;
        }
        __syncthreads();
        for (int i=tid;i<9216;i+=512){
            const int d=i/96, e=i-d*96;
            int s=0;
            #pragma unroll
            for (int wi=0;wi<8;++wi) s += __popc(kb[d][wi] & vb[e][wi]);
            kvl[d][e]=(float)s;
        }
        __syncthreads();
        float val[48];
        #pragma unroll
        for (int e=0;e<48;++e) val[e]=0.f;
        const unsigned char* qcol = qs + base + n;
        #pragma unroll 1
        for (int d=0;d<96;++d){
            const unsigned char qv = qcol[(size_t)d*256];
            if (__any((int)qv)){                   // wave-uniform skip (q sparse)
                const float qf=(float)qv;
                #pragma unroll
                for (int e=0;e<48;++e) val[e] += qf * kvl[d][eh*48+e];
            }
        }
        unsigned char* od = os + base + (size_t)eh*48*256 + n;
        #pragma unroll
        for (int e=0;e<48;++e){
            const float o = val[e]*0.125f;         // exact dyadic
            const float hh = __fadd_rn(vmem[e], __fmul_rn(__fsub_rn(o, vmem[e]), 0.5f));
            const unsigned char s = (hh >= 0.5f) ? 1 : 0;
            vmem[e] = s ? 0.f : hh;
            od[(size_t)e*256] = s;
        }
        __syncthreads();
    }
}

// ---------------------------------------------------------------------------
extern "C" void kernel_launch(void* const* d_in, const int* in_sizes, int n_in,
                              void* d_out, int out_size, void* d_ws, size_t ws_size,
                              hipStream_t stream)
{
    const float* x = (const float*)d_in[0];
    unsigned char* ws8 = (unsigned char*)d_ws;
    unsigned char* xs = ws8;
    unsigned char* qs = ws8 + SP;
    unsigned char* ks = ws8 + 2*SP;
    unsigned char* vs = ws8 + 3*SP;
    unsigned char* os = ws8 + 4*SP;
    float* sbt = (float*)(ws8 + 5*SP);   // [4 sets][2][768]
    float* outp = (float*)d_out;

    // BN scale/bias tables for q,k,v,p (input idx: w=1+5s, g=2+5s, ...)
    for (int s=0;s<4;++s){
        bn_prep<<<3,256,0,stream>>>((const float*)d_in[2+5*s], (const float*)d_in[3+5*s],
                                    (const float*)d_in[4+5*s], (const float*)d_in[5+5*s],
                                    sbt + s*1536);
    }
    head_lif<<<BCN/256,256,0,stream>>>(x, xs);
    conv_bn_k<true><<<dim3(24,16),256,0,stream>>>(xs, (const float*)d_in[1],
                                                  sbt,       qs, (float*)nullptr);
    conv_bn_k<true><<<dim3(24,16),256,0,stream>>>(xs, (const float*)d_in[6],
                                                  sbt+1536,  ks, (float*)nullptr);
    conv_bn_k<true><<<dim3(24,16),256,0,stream>>>(xs, (const float*)d_in[11],
                                                  sbt+3072,  vs, (float*)nullptr);
    attn_fused<<<dim3(16,8),512,0,stream>>>(qs, ks, vs, os);
    conv_bn_k<false><<<dim3(24,64),256,0,stream>>>(os, (const float*)d_in[16],
                                                   sbt+4608, (unsigned char*)nullptr, outp);
}

// Round 2
// 1499.927 us; speedup vs baseline: 21.7660x; 21.7660x over previous
//
#include <hip/hip_runtime.h>

typedef __attribute__((ext_vector_type(8))) short short8;
typedef __attribute__((ext_vector_type(4))) float f32x4;
typedef unsigned int u32;
typedef unsigned long long u64;
typedef unsigned char u8;
typedef unsigned short u16;

#define T_ 4
#define B_ 16
#define C_ 768
#define NPIX 256
#define PLANE (B_*C_*NPIX)                  // 3,145,728 elems per t
static const size_t SPB    = (size_t)T_*PLANE;      // 12,582,912 B (u8 spikes)
static const size_t YBYTES = (size_t)T_*PLANE*4;    // 50,331,648 B (f32 ybuf)
static const int    WELEMS = 9*C_*C_;               // 5,308,416 ushorts
static const size_t WBYTES = (size_t)WELEMS*2;      // 10,616,832 B

__device__ inline u16 f2bf(float f){
    u32 u = __float_as_uint(f);
    u32 r = (u + 0x7FFFu + ((u>>16)&1u)) >> 16;
    return (u16)r;
}
__device__ inline float bf2f(u16 b){ return __uint_as_float((u32)b<<16); }

// ---------------- BN affine: out[0..767]=scale, out[768..1535]=bias --------
__global__ __launch_bounds__(256) void bn_prep(
    const float* __restrict__ g, const float* __restrict__ be,
    const float* __restrict__ m, const float* __restrict__ va,
    float* __restrict__ out)
{
    int i = blockIdx.x*256 + threadIdx.x;
    if (i < C_){
        float s = g[i] / sqrtf(va[i] + 1e-5f);
        out[i] = s;
        out[C_+i] = be[i] - m[i]*s;
    }
}

// ---------------- weight prep: w[co][c][9] f32 -> wt[tap][co][c] bf16 hi/lo -
__global__ __launch_bounds__(256) void wprep(
    const float* __restrict__ w, u16* __restrict__ whi, u16* __restrict__ wlo)
{
    int i = blockIdx.x*256 + threadIdx.x;     // i = co*768 + c, 589824 total
    const float* wp = w + (size_t)i*9;
    #pragma unroll
    for (int tap=0; tap<9; ++tap){
        float wv = wp[tap];
        u16 hb = f2bf(wv);
        float hi = bf2f(hb);
        u16 lb = f2bf(wv - hi);
        whi[(size_t)tap*(C_*C_) + i] = hb;
        wlo[(size_t)tap*(C_*C_) + i] = lb;
    }
}

// ---------------- head LIF: x f32 [img][c][pix] -> spikes u8 same layout ----
__global__ __launch_bounds__(256) void head_lif(
    const float* __restrict__ x, u8* __restrict__ xs)
{
    int i = blockIdx.x*256 + threadIdx.x;
    float v = 0.f;
    #pragma unroll
    for (int t=0;t<4;++t){
        float xv = x[(size_t)t*PLANE + i];
        float hh = __fadd_rn(v, __fmul_rn(__fsub_rn(xv, v), 0.5f));
        u8 s = (hh >= 1.0f) ? 1 : 0;
        v = s ? 0.f : hh;
        xs[(size_t)t*PLANE + i] = s;
    }
}

// ---------------- u8 transpose [img][c][pix] -> [img][pix][c] ---------------
__global__ __launch_bounds__(256) void transpose_cp(
    const u8* __restrict__ in, u8* __restrict__ out)
{
    __shared__ u8 tile[64][68];
    const int tid = threadIdx.x;
    const int c0 = blockIdx.x*64, p0 = blockIdx.y*64, img = blockIdx.z;
    const int row = tid >> 2, seg = tid & 3;
    uint4 r = *(const uint4*)(in + ((size_t)img*C_ + c0+row)*NPIX + p0 + seg*16);
    u32 ws4[4] = {r.x, r.y, r.z, r.w};
    #pragma unroll
    for (int j=0;j<16;++j) tile[row][seg*16+j] = (u8)(ws4[j>>2] >> ((j&3)*8));
    __syncthreads();
    u32 ov[4];
    #pragma unroll
    for (int j=0;j<16;++j){
        u32 v = tile[seg*16+j][row];
        if ((j&3)==0) ov[j>>2] = v; else ov[j>>2] |= v << ((j&3)*8);
    }
    *(uint4*)(out + ((size_t)img*NPIX + p0+row)*C_ + c0 + seg*16)
        = make_uint4(ov[0],ov[1],ov[2],ov[3]);
}

// ---------------- implicit-GEMM MFMA conv3x3 + BN ---------------------------
// A[m=pixel][c] = spikes (pixel-major, shifted per tap), B[c][co] hi/lo bf16.
// Block: 256 thr = 4 waves (2x2), tile BM=128 x BN=64, BK=64.
// EPI=0: write f32 conv+BN to ybuf [img][pix][co]. EPI=1: write d_out [img][co][pix].
template<int EPI>
__global__ __launch_bounds__(256) void conv_mfma(
    const u8* __restrict__ sin, const u16* __restrict__ whi,
    const u16* __restrict__ wlo, const float* __restrict__ sb,
    float* __restrict__ ybuf, float* __restrict__ out)
{
    __shared__ __align__(16) u8 lds[32768];
    u8* As = lds;                // [128][64] bf16, swizzled rows
    u8* Bh = lds + 16384;        // [64 co][64 c] bf16
    u8* Bl = lds + 24576;

    const int tid = threadIdx.x;
    const int co0 = blockIdx.x * 64;
    const int img = blockIdx.y >> 1;
    const int m0  = (blockIdx.y & 1) * 128;
    const int lane = tid & 63, wid = tid >> 6;
    const int wr = wid >> 1, wc = wid & 1;
    const int lrow = lane & 15, lgrp = lane >> 4;

    f32x4 acc[4][2];
    #pragma unroll
    for (int mi=0;mi<4;++mi)
        #pragma unroll
        for (int ni=0;ni<2;++ni)
            #pragma unroll
            for (int r=0;r<4;++r) acc[mi][ni][r] = 0.f;

    const u8* ip = sin + (size_t)img*(NPIX*C_);
    const int sm = tid >> 1, shalf = tid & 1;         // A-stage mapping
    const int py = (m0 + sm) >> 4, px = (m0 + sm) & 15;
    const int brow = tid >> 2, bpart = tid & 3;       // B-stage mapping

    #pragma unroll 1
    for (int tap=0; tap<9; ++tap){
        const int dy = tap/3 - 1, dx = tap - (tap/3)*3 - 1;
        const int sy = py + dy, sx = px + dx;
        const bool valid = ((unsigned)sy < 16u) && ((unsigned)sx < 16u);
        const int soff = valid ? (sy*16+sx)*C_ : 0;
        #pragma unroll 1
        for (int c0=0; c0<C_; c0+=64){
            __syncthreads();
            // stage A: 32 u8 -> 32 bf16 per thread
            {
                u32 wout[16];
                if (valid){
                    const uint4* src = (const uint4*)(ip + soff + c0 + shalf*32);
                    uint4 r0 = src[0], r1 = src[1];
                    u32 inw[8] = {r0.x,r0.y,r0.z,r0.w,r1.x,r1.y,r1.z,r1.w};
                    #pragma unroll
                    for (int q=0;q<8;++q){
                        u32 bb = inw[q];
                        wout[2*q]   = ((bb&1u)        ?0x3F80u:0u) | ((bb&0x100u)    ?0x3F800000u:0u);
                        wout[2*q+1] = ((bb&0x10000u)  ?0x3F80u:0u) | ((bb&0x1000000u)?0x3F800000u:0u);
                    }
                } else {
                    #pragma unroll
                    for (int q=0;q<16;++q) wout[q] = 0u;
                }
                const u32 base = (u32)(sm*128 + shalf*64);
                const u32 swz = (u32)((sm&7)<<4);
                #pragma unroll
                for (int q=0;q<4;++q)
                    *(uint4*)(As + ((base + q*16) ^ swz))
                        = make_uint4(wout[4*q],wout[4*q+1],wout[4*q+2],wout[4*q+3]);
            }
            // stage B hi+lo: 32B each per thread
            {
                const size_t gb = (size_t)tap*(C_*C_) + (size_t)(co0+brow)*C_ + c0 + bpart*16;
                uint4 h0 = *(const uint4*)(whi + gb);
                uint4 h1 = *(const uint4*)(whi + gb + 8);
                uint4 l0 = *(const uint4*)(wlo + gb);
                uint4 l1 = *(const uint4*)(wlo + gb + 8);
                const u32 bb = (u32)(brow*128 + bpart*32);
                const u32 swzb = (u32)((brow&7)<<4);
                *(uint4*)(Bh + ( bb        ^ swzb)) = h0;
                *(uint4*)(Bh + ((bb + 16)  ^ swzb)) = h1;
                *(uint4*)(Bl + ( bb        ^ swzb)) = l0;
                *(uint4*)(Bl + ((bb + 16)  ^ swzb)) = l1;
            }
            __syncthreads();
            // MFMA: 2 k-chunks x (4 mi x 2 ni) x (hi,lo)
            #pragma unroll
            for (int kc=0;kc<2;++kc){
                short8 af[4], bhf[2], blf[2];
                #pragma unroll
                for (int mi=0;mi<4;++mi){
                    int r = wr*64 + mi*16 + lrow;
                    u32 off = (u32)(r*128 + kc*64 + lgrp*16) ^ (u32)((r&7)<<4);
                    af[mi] = *(const short8*)(As + off);
                }
                #pragma unroll
                for (int ni=0;ni<2;++ni){
                    int rc = wc*32 + ni*16 + lrow;
                    u32 off = (u32)(rc*128 + kc*64 + lgrp*16) ^ (u32)((rc&7)<<4);
                    bhf[ni] = *(const short8*)(Bh + off);
                    blf[ni] = *(const short8*)(Bl + off);
                }
                #pragma unroll
                for (int mi=0;mi<4;++mi)
                    #pragma unroll
                    for (int ni=0;ni<2;++ni){
                        acc[mi][ni] = __builtin_amdgcn_mfma_f32_16x16x32_bf16(af[mi], bhf[ni], acc[mi][ni], 0,0,0);
                        acc[mi][ni] = __builtin_amdgcn_mfma_f32_16x16x32_bf16(af[mi], blf[ni], acc[mi][ni], 0,0,0);
                    }
            }
        }
    }
    // epilogue: BN affine, write
    #pragma unroll
    for (int mi=0;mi<4;++mi){
        const int prow = m0 + wr*64 + mi*16 + lgrp*4;
        #pragma unroll
        for (int ni=0;ni<2;++ni){
            const int co = co0 + wc*32 + ni*16 + lrow;
            const float sc = sb[co], bi = sb[C_+co];
            if constexpr (EPI == 0){
                #pragma unroll
                for (int r=0;r<4;++r){
                    float y = __fadd_rn(__fmul_rn(acc[mi][ni][r], sc), bi);
                    ybuf[((size_t)img*NPIX + prow + r)*C_ + co] = y;
                }
            } else {
                f32x4 ov;
                #pragma unroll
                for (int r=0;r<4;++r)
                    ov[r] = __fadd_rn(__fmul_rn(acc[mi][ni][r], sc), bi);
                *(f32x4*)(out + ((size_t)img*C_ + co)*NPIX + prow) = ov;
            }
        }
    }
}

// ---------------- LIF over ybuf -> spikes (pixel-major) ---------------------
__global__ __launch_bounds__(256) void lif_spk(
    const float* __restrict__ y, u8* __restrict__ spk, float vth)
{
    int i = blockIdx.x*256 + threadIdx.x;
    float v = 0.f;
    #pragma unroll
    for (int t=0;t<4;++t){
        float yv = y[(size_t)t*PLANE + i];
        float hh = __fadd_rn(v, __fmul_rn(__fsub_rn(yv, v), 0.5f));
        u8 s = (hh >= vth) ? 1 : 0;
        v = s ? 0.f : hh;
        spk[(size_t)t*PLANE + i] = s;
    }
}

// ---------------- attention: ballot bitmasks + popcount kv + q@kv + LIF -----
// Inputs pixel-major [img][n][c]; block per (b,h), 512 thr.
__global__ __launch_bounds__(512) void attn_fused(
    const u8* __restrict__ qs, const u8* __restrict__ ks,
    const u8* __restrict__ vs, u8* __restrict__ os)
{
    const int tid = threadIdx.x;
    const int b = blockIdx.x, h = blockIdx.y;
    __shared__ u64 kb[96][4], vb[96][4];
    __shared__ float kvl[96][96];
    const int w = tid >> 6, lane = tid & 63;
    const int ng = w & 3, n_build = ng*64 + lane;
    const int n = tid & 255, eh = tid >> 8;
    float vmem[48];
    #pragma unroll
    for (int e=0;e<48;++e) vmem[e]=0.f;

    for (int t=0;t<4;++t){
        const int img = t*16 + b;
        const size_t rbase = ((size_t)img*NPIX)*C_ + (size_t)h*96;
        // build k/v bitmasks over n via ballot (waves 0-3: k, 4-7: v)
        {
            const u8* src = (w < 4 ? ks : vs) + rbase + (size_t)n_build*C_;
            uint4 r[6];
            #pragma unroll
            for (int j=0;j<6;++j) r[j] = ((const uint4*)src)[j];
            u32 wd[24];
            #pragma unroll
            for (int j=0;j<6;++j){ wd[4*j]=r[j].x; wd[4*j+1]=r[j].y; wd[4*j+2]=r[j].z; wd[4*j+3]=r[j].w; }
            u64 (*dst)[4] = (w < 4) ? kb : vb;
            #pragma unroll 1
            for (int d=0; d<96; ++d){
                u32 byte = (wd[d>>2] >> ((d&3)*8)) & 0xFFu;
                u64 m = __ballot((int)byte);
                if (lane == 0) dst[d][ng] = m;
            }
        }
        __syncthreads();
        // kv[d][e] = popcount over n
        for (int i = tid; i < 96*96; i += 512){
            int d = i / 96, e = i - d*96;
            int s = 0;
            #pragma unroll
            for (int g=0; g<4; ++g) s += __popcll(kb[d][g] & vb[e][g]);
            kvl[d][e] = (float)s;
        }
        __syncthreads();
        // o[n][e] = 0.125 * sum_d q[n][d]*kv[d][e], then LIF(0.5)
        {
            const u8* qsrc = qs + rbase + (size_t)n*C_;
            uint4 r[6];
            #pragma unroll
            for (int j=0;j<6;++j) r[j] = ((const uint4*)qsrc)[j];
            u32 qw[24];
            #pragma unroll
            for (int j=0;j<6;++j){ qw[4*j]=r[j].x; qw[4*j+1]=r[j].y; qw[4*j+2]=r[j].z; qw[4*j+3]=r[j].w; }
            float val[48];
            #pragma unroll
            for (int e=0;e<48;++e) val[e]=0.f;
            #pragma unroll 1
            for (int d=0; d<96; ++d){
                u32 qb = (qw[d>>2] >> ((d&3)*8)) & 0xFFu;
                if (__any((int)qb)){
                    float qf = (float)qb;
                    #pragma unroll
                    for (int e=0;e<48;++e) val[e] += qf * kvl[d][eh*48+e];
                }
            }
            uint4 o4[3];
            u32 ow[12];
            #pragma unroll
            for (int e=0;e<48;++e){
                float o = val[e]*0.125f;
                float hh = __fadd_rn(vmem[e], __fmul_rn(__fsub_rn(o, vmem[e]), 0.5f));
                u8 s = (hh >= 0.5f) ? 1 : 0;
                vmem[e] = s ? 0.f : hh;
                if ((e&3)==0) ow[e>>2] = (u32)s; else ow[e>>2] |= ((u32)s) << ((e&3)*8);
            }
            o4[0] = make_uint4(ow[0],ow[1],ow[2],ow[3]);
            o4[1] = make_uint4(ow[4],ow[5],ow[6],ow[7]);
            o4[2] = make_uint4(ow[8],ow[9],ow[10],ow[11]);
            uint4* od = (uint4*)(os + rbase + (size_t)n*C_ + eh*48);
            od[0]=o4[0]; od[1]=o4[1]; od[2]=o4[2];
        }
        __syncthreads();
    }
}

// ---------------------------------------------------------------------------
extern "C" void kernel_launch(void* const* d_in, const int* in_sizes, int n_in,
                              void* d_out, int out_size, void* d_ws, size_t ws_size,
                              hipStream_t stream)
{
    char* base = (char*)d_ws;
    u8* xs_c = (u8*)base;                 // later reused as o_t
    u8* xs_t = (u8*)(base + SPB);
    u8* q_t  = (u8*)(base + 2*SPB);
    u8* k_t  = (u8*)(base + 3*SPB);
    u8* v_t  = (u8*)(base + 4*SPB);
    float* ybuf = (float*)(base + 5*SPB);
    u16* whi = (u16*)(base + 5*SPB + YBYTES);
    u16* wlo = whi + WELEMS;
    float* sbt = (float*)(base + 5*SPB + YBYTES + 2*WBYTES);
    u8* o_t = xs_c;
    float* outp = (float*)d_out;

    for (int s=0;s<4;++s)
        bn_prep<<<3,256,0,stream>>>((const float*)d_in[2+5*s], (const float*)d_in[3+5*s],
                                    (const float*)d_in[4+5*s], (const float*)d_in[5+5*s],
                                    sbt + s*1536);
    head_lif<<<PLANE/256,256,0,stream>>>((const float*)d_in[0], xs_c);
    transpose_cp<<<dim3(12,4,64),256,0,stream>>>(xs_c, xs_t);

    u8* spk_out[3] = {q_t, k_t, v_t};
    for (int s=0;s<3;++s){
        wprep<<<2304,256,0,stream>>>((const float*)d_in[1+5*s], whi, wlo);
        conv_mfma<0><<<dim3(12,128),256,0,stream>>>(xs_t, whi, wlo, sbt + s*1536, ybuf, nullptr);
        lif_spk<<<PLANE/256,256,0,stream>>>(ybuf, spk_out[s], 1.0f);
    }
    attn_fused<<<dim3(16,8),512,0,stream>>>(q_t, k_t, v_t, o_t);
    wprep<<<2304,256,0,stream>>>((const float*)d_in[16], whi, wlo);
    conv_mfma<1><<<dim3(12,128),256,0,stream>>>(o_t, whi, wlo, sbt + 4608, nullptr, outp);
}

// Round 3
// 1326.708 us; speedup vs baseline: 24.6078x; 1.1306x over previous
//
#include <hip/hip_runtime.h>

typedef __attribute__((ext_vector_type(8))) short short8;
typedef __attribute__((ext_vector_type(4))) float f32x4;
typedef unsigned int u32;
typedef unsigned long long u64;
typedef unsigned char u8;
typedef unsigned short u16;

#define T_ 4
#define B_ 16
#define C_ 768
#define NPIX 256
#define PLANE (B_*C_*NPIX)                    // 3,145,728 per t
#define PADPIX 324                            // 18*18
static const size_t SPB    = (size_t)T_*PLANE;          // 12,582,912
static const size_t PADB   = (size_t)64*PADPIX*C_*2;    // 31,850,496
static const size_t YB     = (size_t)T_*PLANE*4;        // 50,331,648
static const int    WELEMS = 9*C_*C_;                    // 5,308,416
static const size_t WBYTES = (size_t)WELEMS*2;           // 10,616,832

__device__ __forceinline__ void gld16(const void* g, void* l){
    __builtin_amdgcn_global_load_lds(
        (const __attribute__((address_space(1))) u32*)g,
        (__attribute__((address_space(3))) u32*)l, 16, 0, 0);
}

__device__ inline u16 f2bf(float f){
    u32 u = __float_as_uint(f);
    return (u16)((u + 0x7FFFu + ((u>>16)&1u)) >> 16);
}
__device__ inline float bf2f(u16 b){ return __uint_as_float((u32)b<<16); }

// ---------------- BN affine ----------------
__global__ __launch_bounds__(256) void bn_prep(
    const float* __restrict__ g, const float* __restrict__ be,
    const float* __restrict__ m, const float* __restrict__ va,
    float* __restrict__ out)
{
    int i = blockIdx.x*256 + threadIdx.x;
    if (i < C_){
        float s = g[i] / sqrtf(va[i] + 1e-5f);
        out[i] = s;
        out[C_+i] = be[i] - m[i]*s;
    }
}

// ---------------- weight prep: f32 [co][c][9] -> bf16 hi/lo [tap][co][c] ----
__global__ __launch_bounds__(256) void wprep(
    const float* __restrict__ w, u16* __restrict__ whi, u16* __restrict__ wlo)
{
    int i = blockIdx.x*256 + threadIdx.x;     // co*768 + c
    const float* wp = w + (size_t)i*9;
    #pragma unroll
    for (int tap=0; tap<9; ++tap){
        float wv = wp[tap];
        u16 hb = f2bf(wv);
        u16 lb = f2bf(wv - bf2f(hb));
        whi[(size_t)tap*(C_*C_) + i] = hb;
        wlo[(size_t)tap*(C_*C_) + i] = lb;
    }
}

// ---------------- head LIF: x f32 [img][c][pix] -> u8 same layout ----------
__global__ __launch_bounds__(256) void head_lif(
    const float* __restrict__ x, u8* __restrict__ xs)
{
    int i = blockIdx.x*256 + threadIdx.x;
    float v = 0.f;
    #pragma unroll
    for (int t=0;t<4;++t){
        float xv = x[(size_t)t*PLANE + i];
        float hh = __fadd_rn(v, __fmul_rn(__fsub_rn(xv, v), 0.5f));
        u8 s = (hh >= 1.0f) ? 1 : 0;
        v = s ? 0.f : hh;
        xs[(size_t)t*PLANE + i] = s;
    }
}

// ------- transpose+pad: u8 [img][c][pix] -> bf16 padded [img][324][c] ------
__global__ __launch_bounds__(256) void pad_xs(
    const u8* __restrict__ in, u16* __restrict__ outp)
{
    __shared__ u8 tile[64][68];
    const int tid = threadIdx.x;
    const int c0 = blockIdx.x*64, p0 = blockIdx.y*64, img = blockIdx.z;
    const int row = tid >> 2, seg = tid & 3;
    uint4 r = *(const uint4*)(in + ((size_t)img*C_ + c0+row)*NPIX + p0 + seg*16);
    u32 ws4[4] = {r.x, r.y, r.z, r.w};
    #pragma unroll
    for (int j=0;j<16;++j) tile[row][seg*16+j] = (u8)(ws4[j>>2] >> ((j&3)*8));
    __syncthreads();
    const int pix = p0 + row;
    const int ppad = ((pix>>4)+1)*18 + (pix&15) + 1;
    u16 vals[16];
    #pragma unroll
    for (int j=0;j<16;++j) vals[j] = tile[seg*16+j][row] ? (u16)0x3F80 : (u16)0;
    u16* dst = outp + (size_t)img*(PADPIX*C_) + (size_t)ppad*C_ + c0 + seg*16;
    *(uint4*)(dst)   = *(uint4*)(&vals[0]);
    *(uint4*)(dst+8) = *(uint4*)(&vals[8]);
}

// ------- o pad: u8 pixel-major [img][pix][c] -> bf16 padded, + img flags ----
__global__ __launch_bounds__(256) void pad_o(
    const u8* __restrict__ o, u16* __restrict__ opad, int* __restrict__ flags)
{
    const int tid = threadIdx.x;
    const int img = blockIdx.y;
    const int off = blockIdx.x*4096 + tid*16;       // elem offset within img
    const int pix = off / C_;
    const int c   = off - pix*C_;
    uint4 r = *(const uint4*)(o + (size_t)img*(NPIX*C_) + off);
    u32 ws4[4] = {r.x, r.y, r.z, r.w};
    u32 any = ws4[0]|ws4[1]|ws4[2]|ws4[3];
    u16 vals[16];
    #pragma unroll
    for (int j=0;j<16;++j)
        vals[j] = ((ws4[j>>2] >> ((j&3)*8)) & 0xFFu) ? (u16)0x3F80 : (u16)0;
    const int ppad = ((pix>>4)+1)*18 + (pix&15) + 1;
    u16* dst = opad + (size_t)img*(PADPIX*C_) + (size_t)ppad*C_ + c;
    *(uint4*)(dst)   = *(uint4*)(&vals[0]);
    *(uint4*)(dst+8) = *(uint4*)(&vals[8]);
    if (__any((int)any) && (tid & 63) == 0) atomicOr(&flags[img], 1);
}

// ---------------- implicit-GEMM MFMA conv3x3 + BN ---------------------------
// A [128 pix][64 c] bf16 from padded buffer, B hi/lo [64 co][64 c].
// 2-phase pipeline: stage next K-step via global_load_lds before computing
// current; one vmcnt(0)+barrier per step (auto at __syncthreads).
template<int EPI>
__global__ __launch_bounds__(256) void conv_mfma(
    const u16* __restrict__ apad, const u16* __restrict__ whi,
    const u16* __restrict__ wlo, const float* __restrict__ sb,
    const int* __restrict__ flags,
    float* __restrict__ ybuf, float* __restrict__ out)
{
    __shared__ __align__(16) u8 lds[2][32768];   // per buf: A 16K | Bh 8K | Bl 8K

    const int tid = threadIdx.x;
    const int bid = blockIdx.x;                   // 0..1535
    const int lid = (bid & 7)*192 + (bid >> 3);   // XCD-chunk swizzle (bijective)
    const int cox = lid >> 7;                     // 0..11 co-tile
    const int mid = lid & 127;
    const int img = mid >> 1;
    const int m0  = (mid & 1) * 128;
    const int co0 = cox * 64;
    const int lane = tid & 63, w = tid >> 6;
    const int wr = w >> 1, wc = w & 1;
    const int lrow = lane & 15, lgrp = lane >> 4;

    if constexpr (EPI == 1){
        if (flags[img] == 0){                     // zero input -> pure BN bias
            for (int k = tid; k < 64*128; k += 256){
                const int co = k >> 7, p = k & 127;
                out[((size_t)img*C_ + co0+co)*NPIX + m0 + p] = sb[C_+co0+co];
            }
            return;
        }
    }

    // per-lane constant source-chunk swizzle: logical chunk = (l&7)^(l>>3)
    const int jb = (((lane & 7) ^ (lane >> 3)) * 16);

    // A per-lane pixel coords for 4 stage-instructions
    int apy[4], apx[4];
    #pragma unroll
    for (int i=0;i<4;++i){
        const int rl = w*32 + i*8 + (lane >> 3);
        const int pg = m0 + rl;
        apy[i] = pg >> 4; apx[i] = pg & 15;
    }
    const u8* abase = (const u8*)apad + (size_t)img*(PADPIX*C_*2);
    const u8* whiB  = (const u8*)whi;
    const u8* wloB  = (const u8*)wlo;
    const int brl0 = w*16 + (lane >> 3);          // B rows (i=0), +8 for i=1

    const u8* aptr[4]; const u8* bhp[2]; const u8* blp[2];
    // init at tap 0 (dy=-1,dx=-1), c0=0
    #pragma unroll
    for (int i=0;i<4;++i)
        aptr[i] = abase + ((size_t)(apy[i]*18 + apx[i])*C_*2) + jb;
    #pragma unroll
    for (int i=0;i<2;++i){
        bhp[i] = whiB + (size_t)(co0 + brl0 + i*8)*(C_*2) + jb;
        blp[i] = wloB + (size_t)(co0 + brl0 + i*8)*(C_*2) + jb;
    }
    int cc = 0, tap = 0;

#define STAGE(B_IDX) {                                                   \
    u8* L = &lds[B_IDX][0];                                              \
    gld16(aptr[0], L + w*4096);                                          \
    gld16(aptr[1], L + w*4096 + 1024);                                   \
    gld16(aptr[2], L + w*4096 + 2048);                                   \
    gld16(aptr[3], L + w*4096 + 3072);                                   \
    gld16(bhp[0], L + 16384 + w*2048);                                   \
    gld16(bhp[1], L + 16384 + w*2048 + 1024);                            \
    gld16(blp[0], L + 24576 + w*2048);                                   \
    gld16(blp[1], L + 24576 + w*2048 + 1024); }

#define ADVANCE {                                                        \
    if (++cc == 12){ cc = 0; ++tap;                                      \
        const int dy = tap/3 - 1, dx = tap - (tap/3)*3 - 1;              \
        _Pragma("unroll")                                                \
        for (int i=0;i<4;++i)                                            \
            aptr[i] = abase + ((size_t)((apy[i]+1+dy)*18 + apx[i]+1+dx)*C_*2) + jb; \
        const size_t wb = (size_t)tap*(C_*C_*2);                         \
        _Pragma("unroll")                                                \
        for (int i=0;i<2;++i){                                           \
            bhp[i] = whiB + wb + (size_t)(co0 + brl0 + i*8)*(C_*2) + jb; \
            blp[i] = wloB + wb + (size_t)(co0 + brl0 + i*8)*(C_*2) + jb; \
        }                                                                \
    } else {                                                             \
        _Pragma("unroll")                                                \
        for (int i=0;i<4;++i) aptr[i] += 128;                            \
        _Pragma("unroll")                                                \
        for (int i=0;i<2;++i){ bhp[i] += 128; blp[i] += 128; }           \
    } }

    f32x4 acc[4][2];
    #pragma unroll
    for (int mi=0;mi<4;++mi)
        #pragma unroll
        for (int ni=0;ni<2;++ni)
            #pragma unroll
            for (int r=0;r<4;++r) acc[mi][ni][r] = 0.f;

    STAGE(0); ADVANCE;
    __syncthreads();                               // vmcnt(0): buf0 ready

    #pragma unroll 1
    for (int s=0; s<108; ++s){
        if (s < 107){ STAGE(s&1 ? 0 : 1); if (s < 106) ADVANCE; }
        const u8* As = &lds[s&1][0];
        const u8* Bh = As + 16384;
        const u8* Bl = As + 24576;
        #pragma unroll
        for (int kc=0;kc<2;++kc){
            short8 af[4], bhf[2], blf[2];
            #pragma unroll
            for (int mi=0;mi<4;++mi){
                const int r = wr*64 + mi*16 + lrow;
                const u32 off = (u32)(r*128 + kc*64 + lgrp*16) ^ (u32)((r&7)<<4);
                af[mi] = *(const short8*)(As + off);
            }
            #pragma unroll
            for (int ni=0;ni<2;++ni){
                const int rc = wc*32 + ni*16 + lrow;
                const u32 off = (u32)(rc*128 + kc*64 + lgrp*16) ^ (u32)((rc&7)<<4);
                bhf[ni] = *(const short8*)(Bh + off);
                blf[ni] = *(const short8*)(Bl + off);
            }
            __builtin_amdgcn_s_setprio(1);
            #pragma unroll
            for (int mi=0;mi<4;++mi)
                #pragma unroll
                for (int ni=0;ni<2;++ni){
                    acc[mi][ni] = __builtin_amdgcn_mfma_f32_16x16x32_bf16(af[mi], bhf[ni], acc[mi][ni], 0,0,0);
                    acc[mi][ni] = __builtin_amdgcn_mfma_f32_16x16x32_bf16(af[mi], blf[ni], acc[mi][ni], 0,0,0);
                }
            __builtin_amdgcn_s_setprio(0);
        }
        __syncthreads();                           // vmcnt(0)+lgkmcnt(0) drain
    }
#undef STAGE
#undef ADVANCE

    #pragma unroll
    for (int mi=0;mi<4;++mi){
        const int prow = m0 + wr*64 + mi*16 + lgrp*4;
        #pragma unroll
        for (int ni=0;ni<2;++ni){
            const int co = co0 + wc*32 + ni*16 + lrow;
            const float sc = sb[co], bi = sb[C_+co];
            if constexpr (EPI == 0){
                #pragma unroll
                for (int r=0;r<4;++r){
                    float y = __fadd_rn(__fmul_rn(acc[mi][ni][r], sc), bi);
                    ybuf[((size_t)img*NPIX + prow + r)*C_ + co] = y;
                }
            } else {
                f32x4 ov;
                #pragma unroll
                for (int r=0;r<4;++r)
                    ov[r] = __fadd_rn(__fmul_rn(acc[mi][ni][r], sc), bi);
                *(f32x4*)(out + ((size_t)img*C_ + co)*NPIX + prow) = ov;
            }
        }
    }
}

// ---------------- LIF over ybuf [img][pix][c] -> u8 spikes same layout ------
__global__ __launch_bounds__(256) void lif_spk(
    const float* __restrict__ y, u8* __restrict__ spk, float vth)
{
    int i = blockIdx.x*256 + threadIdx.x;
    float v = 0.f;
    #pragma unroll
    for (int t=0;t<4;++t){
        float yv = y[(size_t)t*PLANE + i];
        float hh = __fadd_rn(v, __fmul_rn(__fsub_rn(yv, v), 0.5f));
        u8 s = (hh >= vth) ? 1 : 0;
        v = s ? 0.f : hh;
        spk[(size_t)t*PLANE + i] = s;
    }
}

// ---------------- attention (pixel-major inputs/outputs) --------------------
__global__ __launch_bounds__(512) void attn_fused(
    const u8* __restrict__ qs, const u8* __restrict__ ks,
    const u8* __restrict__ vs, u8* __restrict__ os)
{
    const int tid = threadIdx.x;
    const int b = blockIdx.x, h = blockIdx.y;
    __shared__ u64 kb[96][4], vb[96][4];
    __shared__ float kvl[96][96];
    const int w = tid >> 6, lane = tid & 63;
    const int ng = w & 3, n_build = ng*64 + lane;
    const int n = tid & 255, eh = tid >> 8;
    float vmem[48];
    #pragma unroll
    for (int e=0;e<48;++e) vmem[e]=0.f;

    for (int t=0;t<4;++t){
        const int img = t*16 + b;
        const size_t rbase = ((size_t)img*NPIX)*C_ + (size_t)h*96;
        {
            const u8* src = (w < 4 ? ks : vs) + rbase + (size_t)n_build*C_;
            uint4 r[6];
            #pragma unroll
            for (int j=0;j<6;++j) r[j] = ((const uint4*)src)[j];
            u32 wd[24];
            #pragma unroll
            for (int j=0;j<6;++j){ wd[4*j]=r[j].x; wd[4*j+1]=r[j].y; wd[4*j+2]=r[j].z; wd[4*j+3]=r[j].w; }
            u64 (*dst)[4] = (w < 4) ? kb : vb;
            #pragma unroll 1
            for (int d=0; d<96; ++d){
                u32 byte = (wd[d>>2] >> ((d&3)*8)) & 0xFFu;
                u64 m = __ballot((int)byte);
                if (lane == 0) dst[d][ng] = m;
            }
        }
        __syncthreads();
        for (int i = tid; i < 96*96; i += 512){
            int d = i / 96, e = i - d*96;
            int s = 0;
            #pragma unroll
            for (int g=0; g<4; ++g) s += __popcll(kb[d][g] & vb[e][g]);
            kvl[d][e] = (float)s;
        }
        __syncthreads();
        {
            const u8* qsrc = qs + rbase + (size_t)n*C_;
            uint4 r[6];
            #pragma unroll
            for (int j=0;j<6;++j) r[j] = ((const uint4*)qsrc)[j];
            u32 qw[24];
            #pragma unroll
            for (int j=0;j<6;++j){ qw[4*j]=r[j].x; qw[4*j+1]=r[j].y; qw[4*j+2]=r[j].z; qw[4*j+3]=r[j].w; }
            float val[48];
            #pragma unroll
            for (int e=0;e<48;++e) val[e]=0.f;
            #pragma unroll 1
            for (int d=0; d<96; ++d){
                u32 qb = (qw[d>>2] >> ((d&3)*8)) & 0xFFu;
                if (__any((int)qb)){
                    float qf = (float)qb;
                    #pragma unroll
                    for (int e=0;e<48;++e) val[e] += qf * kvl[d][eh*48+e];
                }
            }
            u32 ow[12];
            #pragma unroll
            for (int e=0;e<48;++e){
                float o = val[e]*0.125f;
                float hh = __fadd_rn(vmem[e], __fmul_rn(__fsub_rn(o, vmem[e]), 0.5f));
                u8 s = (hh >= 0.5f) ? 1 : 0;
                vmem[e] = s ? 0.f : hh;
                if ((e&3)==0) ow[e>>2] = (u32)s; else ow[e>>2] |= ((u32)s) << ((e&3)*8);
            }
            uint4* od = (uint4*)(os + rbase + (size_t)n*C_ + eh*48);
            od[0] = make_uint4(ow[0],ow[1],ow[2],ow[3]);
            od[1] = make_uint4(ow[4],ow[5],ow[6],ow[7]);
            od[2] = make_uint4(ow[8],ow[9],ow[10],ow[11]);
        }
        __syncthreads();
    }
}

// ---------------------------------------------------------------------------
extern "C" void kernel_launch(void* const* d_in, const int* in_sizes, int n_in,
                              void* d_out, int out_size, void* d_ws, size_t ws_size,
                              hipStream_t stream)
{
    char* base = (char*)d_ws;
    // region map (143.2 MB total, aggressive reuse):
    u8*  xs_c  = (u8*)base;                          // 12.58M (dead after pad_xs)
    u16* whi   = (u16*)base;                         // overlays xs_c after pad_xs
    u16* wlo   = (u16*)(base + 12582912);            // 10.62M
    float* sbt = (float*)(base + 23199744);          // 24.6K
    int* flags = (int*)(base + 23224320);            // 256B
    u8*  q_t   = (u8*)(base + 23224832);
    u8*  k_t   = (u8*)(base + 35807744);
    u8*  v_t   = (u8*)(base + 48390656);
    u16* apadA = (u16*)(base + 60973568);            // 31.85M: xs_pad then o_pad
    float* ybuf= (float*)(base + 92824064);          // 50.33M: ybuf then o_u8
    u8*  o_u8  = (u8*)ybuf;
    float* outp = (float*)d_out;

    for (int s=0;s<4;++s)
        bn_prep<<<3,256,0,stream>>>((const float*)d_in[2+5*s], (const float*)d_in[3+5*s],
                                    (const float*)d_in[4+5*s], (const float*)d_in[5+5*s],
                                    sbt + s*1536);
    hipMemsetAsync(apadA, 0, PADB, stream);
    hipMemsetAsync(flags, 0, 256, stream);
    head_lif<<<PLANE/256,256,0,stream>>>((const float*)d_in[0], xs_c);
    pad_xs<<<dim3(12,4,64),256,0,stream>>>(xs_c, apadA);

    u8* spk_out[3] = {q_t, k_t, v_t};
    for (int s=0;s<3;++s){
        wprep<<<2304,256,0,stream>>>((const float*)d_in[1+5*s], whi, wlo);
        conv_mfma<0><<<1536,256,0,stream>>>(apadA, whi, wlo, sbt + s*1536, flags, ybuf, nullptr);
        lif_spk<<<PLANE/256,256,0,stream>>>(ybuf, spk_out[s], 1.0f);
    }
    attn_fused<<<dim3(16,8),512,0,stream>>>(q_t, k_t, v_t, o_u8);
    hipMemsetAsync(apadA, 0, PADB, stream);              // reuse as o_pad
    pad_o<<<dim3(48,64),256,0,stream>>>(o_u8, apadA, flags);
    wprep<<<2304,256,0,stream>>>((const float*)d_in[16], whi, wlo);
    conv_mfma<1><<<1536,256,0,stream>>>(apadA, whi, wlo, sbt + 4608, flags, nullptr, outp);
}

// Round 4
// 930.556 us; speedup vs baseline: 35.0837x; 1.4257x over previous
//
#include <hip/hip_runtime.h>

typedef __attribute__((ext_vector_type(8))) short short8;
typedef __attribute__((ext_vector_type(4))) float f32x4;
typedef unsigned int u32;
typedef unsigned long long u64;
typedef unsigned char u8;
typedef unsigned short u16;

#define C_ 768
#define NPIX 256
#define PLANE (16*C_*NPIX)
#define ROWB 96            // bytes per padded bit-row (global, 768 bits)
#define ROWL 112           // LDS row stride (bank-friendly: 28 banks -> 2-way max)
#define IMGBITS (324*ROWB) // 31104 B per image

// workspace offsets (total ~131.9 MB)
#define OFF_WFRAG 0ull           // 21,233,664  (9 tap x 768c x 768co hi+lo bf16, frag order)
#define OFF_YBUF  21233664ull    // 50,331,648  f32 [img][pix][co]
#define OFF_QU8   71565312ull    // 12,582,912  u8 [img][pix][c]
#define OFF_KU8   84148224ull
#define OFF_VU8   96731136ull
#define OFF_OU8   109314048ull
#define OFF_BITS  121896960ull   // 5 x 1,990,656 (xs,q,k,v,o bit-planes, contiguous)
#define BITSZ     1990656ull
#define OFF_SBT   131850240ull   // 4 x 1536 f32
#define OFF_FLAGS 131874816ull   // 64 int

__device__ __forceinline__ u16 f2bf(float f){
    u32 u = __float_as_uint(f);
    return (u16)((u + 0x7FFFu + ((u>>16)&1u)) >> 16);
}
__device__ __forceinline__ float bf2f(u16 b){ return __uint_as_float((u32)b<<16); }
__device__ __forceinline__ short8 as_s8(uint4 v){ union{uint4 u; short8 s;} c; c.u=v; return c.s; }

// ---------------- BN affine: [0..767]=scale, [768..1535]=bias ---------------
__global__ __launch_bounds__(256) void bn_prep(
    const float* __restrict__ g, const float* __restrict__ be,
    const float* __restrict__ m, const float* __restrict__ va,
    float* __restrict__ out)
{
    int i = blockIdx.x*256 + threadIdx.x;
    if (i < C_){
        float s = g[i] / sqrtf(va[i] + 1e-5f);
        out[i] = s;
        out[C_+i] = be[i] - m[i]*s;
    }
}

// -------- weight prep: w f32 [co][c][9] -> fragment-ordered bf16 hi/lo ------
// word(cch,tap,kc,nfg,hl)[lane] = w_hl[tap][nfg*16+(lane&15)][cch*64+kc*32+(lane>>4)*8+e]
__global__ __launch_bounds__(256) void wprep(
    const float* __restrict__ w, u8* __restrict__ wf)
{
    int gid = blockIdx.x*256 + threadIdx.x;      // 73728 = 768co x 96(c8)
    int co = gid / 96, c8 = gid - co*96;
    int cch = c8 >> 3, kc = (c8 >> 2) & 1, lane = (co & 15) | ((c8 & 3) << 4);
    int nfg = co >> 4;
    const float* wp = w + (size_t)co*6912 + (size_t)c8*72;   // 8 c-elems x 9 taps
    #pragma unroll 1
    for (int tap=0; tap<9; ++tap){
        u32 hw[4], lw[4];
        #pragma unroll
        for (int q=0;q<4;++q){
            float f0 = wp[(2*q)*9 + tap], f1 = wp[(2*q+1)*9 + tap];
            u16 h0 = f2bf(f0), h1 = f2bf(f1);
            u16 l0 = f2bf(f0 - bf2f(h0)), l1 = f2bf(f1 - bf2f(h1));
            hw[q] = (u32)h0 | ((u32)h1 << 16);
            lw[q] = (u32)l0 | ((u32)l1 << 16);
        }
        size_t base = ((((size_t)(cch*9+tap)*2 + kc)*48 + nfg)*2)*1024 + (size_t)lane*16;
        *(uint4*)(wf + base)        = make_uint4(hw[0],hw[1],hw[2],hw[3]);
        *(uint4*)(wf + base + 1024) = make_uint4(lw[0],lw[1],lw[2],lw[3]);
    }
}

// ------- head LIF: x f32 [img][c][pix] -> padded bit rows [img][324][96] ----
__global__ __launch_bounds__(256) void head_bits(
    const float* __restrict__ x, u8* __restrict__ bits)
{
    int gid = blockIdx.x*256 + threadIdx.x;      // 16b x 96cb x 256pix
    int b = gid / 24576, rem = gid - b*24576;
    int cb = rem >> 8, pix = rem & 255;
    int pr = ((pix>>4)+1)*18 + (pix&15) + 1;
    float v[8];
    #pragma unroll
    for (int j=0;j<8;++j) v[j]=0.f;
    #pragma unroll
    for (int t=0;t<4;++t){
        int img = t*16 + b;
        u32 byte = 0;
        #pragma unroll
        for (int j=0;j<8;++j){
            float xv = x[((size_t)img*C_ + cb*8 + j)*NPIX + pix];
            float h = __fadd_rn(v[j], __fmul_rn(__fsub_rn(xv, v[j]), 0.5f));
            u32 s = (h >= 1.0f) ? 1u : 0u;
            v[j] = s ? 0.f : h;
            byte |= s << j;
        }
        bits[(size_t)img*IMGBITS + (size_t)pr*ROWB + cb] = (u8)byte;
    }
}

// ---------------- implicit-GEMM conv3x3 + BN, bit-A / global-frag-B ---------
// Block: 256 thr (4 waves, 2m x 2n), tile 256 pix x 96 co, grid 512 (img x 8 cox).
// A: whole padded image bit-plane in LDS (36 KB), read 1 byte/lane per frag,
//    expanded to bf16 in VALU. B: hi/lo frag-words streamed from L2 into regs,
//    one kc-step ahead. NO barriers in main loop.
template<int EPI>
__global__ __launch_bounds__(256,2) void conv_mfma(
    const u8* __restrict__ abits, const u8* __restrict__ wf,
    const float* __restrict__ sb, const int* __restrict__ flags,
    float* __restrict__ ybuf, float* __restrict__ out)
{
    __shared__ __align__(16) u8 Ab[324*ROWL];
    const int tid = threadIdx.x;
    const int cox = blockIdx.x & 7, img = blockIdx.x >> 3;
    const int lane = tid & 63, w = tid >> 6;
    const int wr = w >> 1, wc = w & 1;
    const int lrow = lane & 15, lgrp = lane >> 4;

    if constexpr (EPI == 1){
        if (flags[img] == 0){                    // zero input -> pure BN bias
            #pragma unroll 1
            for (int idx = tid; idx < 96*64; idx += 256){
                int row = idx >> 6, seg = idx & 63;
                int co = cox*96 + row;
                float bv = sb[C_ + co];
                f32x4 v; v[0]=bv; v[1]=bv; v[2]=bv; v[3]=bv;
                *(f32x4*)(out + ((size_t)img*C_ + co)*NPIX + seg*4) = v;
            }
            return;
        }
    }

    {   // stage the image's bit-plane: 324 rows x 96 B -> stride-112 LDS
        const u8* src = abits + (size_t)img*IMGBITS;
        #pragma unroll 1
        for (int r = tid; r < 324; r += 256){
            const u8* s = src + r*ROWB;
            u8* d = Ab + r*ROWL;
            #pragma unroll
            for (int j=0;j<6;++j)
                *(uint4*)(d + j*16) = *(const uint4*)(s + j*16);
        }
    }
    __syncthreads();

    int rb[8];                                    // per-lane row base byte addr
    #pragma unroll
    for (int mi=0;mi<8;++mi){
        int p = wr*128 + mi*16 + lrow;
        rb[mi] = (((p>>4)+1)*18 + (p&15) + 1)*ROWL + lgrp;
    }

    f32x4 acc[8][3];
    #pragma unroll
    for (int mi=0;mi<8;++mi)
        #pragma unroll
        for (int ni=0;ni<3;++ni)
            #pragma unroll
            for (int r=0;r<4;++r) acc[mi][ni][r]=0.f;

    const u8* wp = wf + (size_t)cox*12288 + (size_t)wc*6144 + (size_t)lane*16;

    uint4 B0[6], B1[6];

#define LOADB(BUF) { \
    _Pragma("unroll") \
    for (int j=0;j<6;++j) BUF[j] = *(const uint4*)(wp + (j>>1)*2048 + (j&1)*1024); \
    wp += 98304; }

#define COMPUTE(BUF, OFFB) { \
    short8 af[8]; \
    _Pragma("unroll") \
    for (int mi=0;mi<8;++mi){ \
        u32 xb = (u32)Ab[rb[mi] + (OFFB)]; \
        u32 rr0, rr1, rr2, rr3; \
        { u32 t=(xb    )&3u; u32 uu=((u32)__mul24((int)t,0x8001))&0x10001u; rr0=(u32)__mul24((int)uu,16256); } \
        { u32 t=(xb>>2 )&3u; u32 uu=((u32)__mul24((int)t,0x8001))&0x10001u; rr1=(u32)__mul24((int)uu,16256); } \
        { u32 t=(xb>>4 )&3u; u32 uu=((u32)__mul24((int)t,0x8001))&0x10001u; rr2=(u32)__mul24((int)uu,16256); } \
        { u32 t=(xb>>6 )&3u; u32 uu=((u32)__mul24((int)t,0x8001))&0x10001u; rr3=(u32)__mul24((int)uu,16256); } \
        uint4 ua; ua.x=rr0; ua.y=rr1; ua.z=rr2; ua.w=rr3; \
        af[mi] = as_s8(ua); \
    } \
    __builtin_amdgcn_s_setprio(1); \
    _Pragma("unroll") \
    for (int mi=0;mi<8;++mi){ \
        _Pragma("unroll") \
        for (int ni=0;ni<3;++ni){ \
            acc[mi][ni] = __builtin_amdgcn_mfma_f32_16x16x32_bf16(af[mi], as_s8(BUF[ni*2+0]), acc[mi][ni], 0,0,0); \
            acc[mi][ni] = __builtin_amdgcn_mfma_f32_16x16x32_bf16(af[mi], as_s8(BUF[ni*2+1]), acc[mi][ni], 0,0,0); \
        } \
    } \
    __builtin_amdgcn_s_setprio(0); }

    LOADB(B0);
    const int dtab[9] = {-19,-18,-17,-1,0,1,17,18,19};
    #pragma unroll 1
    for (int cch=0; cch<12; ++cch){
        #pragma unroll 1
        for (int tap=0; tap<9; ++tap){
            const int so = dtab[tap]*ROWL + cch*8;
            LOADB(B1);                 // prefetch kc=1 of this step
            COMPUTE(B0, so);           // kc=0
            LOADB(B0);                 // prefetch kc=0 of next step
            COMPUTE(B1, so + 4);       // kc=1
        }
    }
#undef LOADB
#undef COMPUTE

    #pragma unroll
    for (int mi=0;mi<8;++mi){
        const int prow = wr*128 + mi*16 + lgrp*4;
        #pragma unroll
        for (int ni=0;ni<3;++ni){
            const int co = cox*96 + wc*48 + ni*16 + lrow;
            const float sc = sb[co], bi = sb[C_ + co];
            if constexpr (EPI == 0){
                #pragma unroll
                for (int r=0;r<4;++r)
                    ybuf[((size_t)img*NPIX + prow + r)*C_ + co] =
                        __fadd_rn(__fmul_rn(acc[mi][ni][r], sc), bi);
            } else {
                f32x4 ov;
                #pragma unroll
                for (int r=0;r<4;++r) ov[r] = __fadd_rn(__fmul_rn(acc[mi][ni][r], sc), bi);
                *(f32x4*)(out + ((size_t)img*C_ + co)*NPIX + prow) = ov;
            }
        }
    }
}

// ---- LIF over ybuf -> u8 plane (for attn) + padded bit rows (for conv) -----
__global__ __launch_bounds__(256) void lif_bits(
    const float* __restrict__ y, u8* __restrict__ su8, u8* __restrict__ bits)
{
    int gid = blockIdx.x*256 + threadIdx.x;      // 16b x 256pix x 96cb
    int b = gid / 24576, rem = gid - b*24576;
    int pix = rem / 96, cb = rem - pix*96;
    int pr = ((pix>>4)+1)*18 + (pix&15) + 1;
    float v[8];
    #pragma unroll
    for (int j=0;j<8;++j) v[j]=0.f;
    #pragma unroll
    for (int t=0;t<4;++t){
        int img = t*16 + b;
        const float* yp = y + ((size_t)img*NPIX + pix)*C_ + cb*8;
        f32x4 y0 = *(const f32x4*)yp;
        f32x4 y1 = *(const f32x4*)(yp + 4);
        u32 byte = 0, w0 = 0, w1 = 0;
        #pragma unroll
        for (int j=0;j<8;++j){
            float yv = (j<4) ? y0[j] : y1[j-4];
            float h = __fadd_rn(v[j], __fmul_rn(__fsub_rn(yv, v[j]), 0.5f));
            u32 s = (h >= 1.0f) ? 1u : 0u;
            v[j] = s ? 0.f : h;
            byte |= s << j;
            if (j<4) w0 |= s << (j*8); else w1 |= s << ((j-4)*8);
        }
        *(uint2*)(su8 + ((size_t)img*NPIX + pix)*C_ + cb*8) = make_uint2(w0,w1);
        bits[(size_t)img*IMGBITS + (size_t)pr*ROWB + cb] = (u8)byte;
    }
}

// ---- o u8 pixel-major -> padded bit rows + per-image any-spike flags -------
__global__ __launch_bounds__(256) void pad_o_bits(
    const u8* __restrict__ o, u8* __restrict__ bits, int* __restrict__ flags)
{
    int gid = blockIdx.x*256 + threadIdx.x;      // 64img x 256pix x 96cb
    int img = gid / 24576, rem = gid - img*24576;
    int pix = rem / 96, cb = rem - pix*96;
    int pr = ((pix>>4)+1)*18 + (pix&15) + 1;
    uint2 r = *(const uint2*)(o + ((size_t)img*NPIX + pix)*C_ + cb*8);
    u32 byte = 0;
    #pragma unroll
    for (int j=0;j<4;++j){
        byte |= ((r.x >> (j*8)) & 1u) << j;
        byte |= ((r.y >> (j*8)) & 1u) << (j+4);
    }
    bits[(size_t)img*IMGBITS + (size_t)pr*ROWB + cb] = (u8)byte;
    if (__any((int)(r.x | r.y)) && (threadIdx.x & 63) == 0)
        atomicOr(&flags[img], 1);
}

// ---------------- attention (verbatim from verified round 3) ----------------
__global__ __launch_bounds__(512) void attn_fused(
    const u8* __restrict__ qs, const u8* __restrict__ ks,
    const u8* __restrict__ vs, u8* __restrict__ os)
{
    const int tid = threadIdx.x;
    const int b = blockIdx.x, h = blockIdx.y;
    __shared__ u64 kb[96][4], vb[96][4];
    __shared__ float kvl[96][96];
    const int w = tid >> 6, lane = tid & 63;
    const int ng = w & 3, n_build = ng*64 + lane;
    const int n = tid & 255, eh = tid >> 8;
    float vmem[48];
    #pragma unroll
    for (int e=0;e<48;++e) vmem[e]=0.f;

    for (int t=0;t<4;++t){
        const int img = t*16 + b;
        const size_t rbase = ((size_t)img*NPIX)*C_ + (size_t)h*96;
        {
            const u8* src = (w < 4 ? ks : vs) + rbase + (size_t)n_build*C_;
            uint4 r[6];
            #pragma unroll
            for (int j=0;j<6;++j) r[j] = ((const uint4*)src)[j];
            u32 wd[24];
            #pragma unroll
            for (int j=0;j<6;++j){ wd[4*j]=r[j].x; wd[4*j+1]=r[j].y; wd[4*j+2]=r[j].z; wd[4*j+3]=r[j].w; }
            u64 (*dst)[4] = (w < 4) ? kb : vb;
            #pragma unroll 1
            for (int d=0; d<96; ++d){
                u32 byte = (wd[d>>2] >> ((d&3)*8)) & 0xFFu;
                u64 m = __ballot((int)byte);
                if (lane == 0) dst[d][ng] = m;
            }
        }
        __syncthreads();
        for (int i = tid; i < 96*96; i += 512){
            int d = i / 96, e = i - d*96;
            int s = 0;
            #pragma unroll
            for (int g=0; g<4; ++g) s += __popcll(kb[d][g] & vb[e][g]);
            kvl[d][e] = (float)s;
        }
        __syncthreads();
        {
            const u8* qsrc = qs + rbase + (size_t)n*C_;
            uint4 r[6];
            #pragma unroll
            for (int j=0;j<6;++j) r[j] = ((const uint4*)qsrc)[j];
            u32 qw[24];
            #pragma unroll
            for (int j=0;j<6;++j){ qw[4*j]=r[j].x; qw[4*j+1]=r[j].y; qw[4*j+2]=r[j].z; qw[4*j+3]=r[j].w; }
            float val[48];
            #pragma unroll
            for (int e=0;e<48;++e) val[e]=0.f;
            #pragma unroll 1
            for (int d=0; d<96; ++d){
                u32 qb = (qw[d>>2] >> ((d&3)*8)) & 0xFFu;
                if (__any((int)qb)){
                    float qf = (float)qb;
                    #pragma unroll
                    for (int e=0;e<48;++e) val[e] += qf * kvl[d][eh*48+e];
                }
            }
            u32 ow[12];
            #pragma unroll
            for (int e=0;e<48;++e){
                float o = val[e]*0.125f;
                float hh = __fadd_rn(vmem[e], __fmul_rn(__fsub_rn(o, vmem[e]), 0.5f));
                u8 s = (hh >= 0.5f) ? 1 : 0;
                vmem[e] = s ? 0.f : hh;
                if ((e&3)==0) ow[e>>2] = (u32)s; else ow[e>>2] |= ((u32)s) << ((e&3)*8);
            }
            uint4* od = (uint4*)(os + rbase + (size_t)n*C_ + eh*48);
            od[0] = make_uint4(ow[0],ow[1],ow[2],ow[3]);
            od[1] = make_uint4(ow[4],ow[5],ow[6],ow[7]);
            od[2] = make_uint4(ow[8],ow[9],ow[10],ow[11]);
        }
        __syncthreads();
    }
}

// ---------------------------------------------------------------------------
extern "C" void kernel_launch(void* const* d_in, const int* in_sizes, int n_in,
                              void* d_out, int out_size, void* d_ws, size_t ws_size,
                              hipStream_t stream)
{
    u8* ws = (u8*)d_ws;
    u8* wfrag   = ws + OFF_WFRAG;
    float* ybuf = (float*)(ws + OFF_YBUF);
    u8* q_u8 = ws + OFF_QU8;
    u8* k_u8 = ws + OFF_KU8;
    u8* v_u8 = ws + OFF_VU8;
    u8* o_u8 = ws + OFF_OU8;
    u8* xs_b = ws + OFF_BITS;
    u8* q_b  = ws + OFF_BITS + 1*BITSZ;
    u8* k_b  = ws + OFF_BITS + 2*BITSZ;
    u8* v_b  = ws + OFF_BITS + 3*BITSZ;
    u8* o_b  = ws + OFF_BITS + 4*BITSZ;
    float* sbt = (float*)(ws + OFF_SBT);
    int* flags = (int*)(ws + OFF_FLAGS);
    float* outp = (float*)d_out;

    hipMemsetAsync(ws + OFF_BITS, 0, 5*BITSZ, stream);   // bit halos must be 0
    hipMemsetAsync(ws + OFF_FLAGS, 0, 256, stream);

    for (int s=0;s<4;++s)
        bn_prep<<<3,256,0,stream>>>((const float*)d_in[2+5*s], (const float*)d_in[3+5*s],
                                    (const float*)d_in[4+5*s], (const float*)d_in[5+5*s],
                                    sbt + s*1536);
    head_bits<<<1536,256,0,stream>>>((const float*)d_in[0], xs_b);

    u8* u8p[3]  = {q_u8, k_u8, v_u8};
    u8* bitp[3] = {q_b, k_b, v_b};
    for (int s=0;s<3;++s){
        wprep<<<288,256,0,stream>>>((const float*)d_in[1+5*s], wfrag);
        conv_mfma<0><<<512,256,0,stream>>>(xs_b, wfrag, sbt + s*1536, nullptr, ybuf, nullptr);
        lif_bits<<<1536,256,0,stream>>>(ybuf, u8p[s], bitp[s]);
    }
    attn_fused<<<dim3(16,8),512,0,stream>>>(q_u8, k_u8, v_u8, o_u8);
    pad_o_bits<<<6144,256,0,stream>>>(o_u8, o_b, flags);
    wprep<<<288,256,0,stream>>>((const float*)d_in[16], wfrag);
    conv_mfma<1><<<512,256,0,stream>>>(o_b, wfrag, sbt + 4608, flags, nullptr, outp);
}

// Round 5
// 683.241 us; speedup vs baseline: 47.7831x; 1.3620x over previous
//
#include <hip/hip_runtime.h>

typedef __attribute__((ext_vector_type(4))) int   i32x4;
typedef __attribute__((ext_vector_type(4))) float f32x4;
typedef unsigned int u32;
typedef unsigned long long u64;
typedef unsigned char u8;
typedef unsigned short u16;

#define C_ 768
#define NPIX 256
#define PLANE (16*C_*NPIX)
#define ROWB 96            // bytes per padded bit-row (global)
#define ROWL 112           // LDS bit-row stride
#define IMGBITS (324*ROWB) // 31104 B per image
#define AEXP_STRIDE 80     // expanded i8 row stride (2-way-conflict-free)
#define AEXP_SZ 14400      // 10 rows x 18 px x 80 B

// workspace map
#define OFF_WFRAG 0ull            // 10,616,832 (9tap x 768co x 768c, i8 hi+lo, frag order)
#define OFF_YBUF  10616832ull     // 50,331,648 f32
#define OFF_QU8   60948480ull     // 12,582,912 each
#define OFF_KU8   73531392ull
#define OFF_VU8   86114304ull
#define OFF_OU8   98697216ull
#define OFF_BITS  111280128ull    // 5 x 1,990,656
#define BITSZ     1990656ull
#define OFF_SBT   121233408ull    // 4 x 1536 f32
#define OFF_FLAGS 121257984ull    // 64 int
#define OFF_WMAX  121258240ull    // 4 f32

__device__ __forceinline__ i32x4 as_i4(uint4 v){ union{uint4 u; i32x4 s;} c; c.u=v; return c.s; }
#define SPREAD(NIB) ((u32)__mul24((int)(NIB), 0x204081) & 0x01010101u)

// ---------------- BN affine: [0..767]=scale, [768..1535]=bias ---------------
__global__ __launch_bounds__(256) void bn_prep(
    const float* __restrict__ g, const float* __restrict__ be,
    const float* __restrict__ m, const float* __restrict__ va,
    float* __restrict__ out)
{
    int i = blockIdx.x*256 + threadIdx.x;
    if (i < C_){
        float s = g[i] / sqrtf(va[i] + 1e-5f);
        out[i] = s;
        out[C_+i] = be[i] - m[i]*s;
    }
}

// ---------------- max|w| reduction (for dynamic i16 scale) ------------------
__global__ __launch_bounds__(256) void wmax_k(
    const float* __restrict__ w, int n, float* __restrict__ out)
{
    float m = 0.f;
    for (int i = blockIdx.x*256 + threadIdx.x; i < n; i += 131072)
        m = fmaxf(m, fabsf(w[i]));
    #pragma unroll
    for (int off = 32; off >= 1; off >>= 1)
        m = fmaxf(m, __shfl_xor(m, off));
    if ((threadIdx.x & 63) == 0)
        atomicMax((int*)out, __float_as_int(m));
}

// ---- weight prep: f32 [co][c][9] -> i8 hi/lo fragment-ordered --------------
// frag addr = (((cch*9+tap)*48 + nfg)*2 + hl)*1024 + lane*16
// lane = (co&15) | ((c16&3)<<4); byte e = w_hl[tap][co][cch*64+(lane>>4)*16+e]
__global__ __launch_bounds__(256) void wprep(
    const float* __restrict__ w, const float* __restrict__ wmaxp,
    u8* __restrict__ wf)
{
    int gid = blockIdx.x*256 + threadIdx.x;     // 36864 = 768co x 48 c16
    int co = gid / 48, c16 = gid - co*48;
    float mw = *wmaxp;
    float invS = (mw > 0.f) ? (32512.0f / mw) : 0.f;
    int cch = c16 >> 2;
    int lane = (co & 15) | ((c16 & 3) << 4);
    int nfg = co >> 4;
    const float* wp = w + (size_t)co*6912 + (size_t)c16*144;   // 16 c x 9 taps
    #pragma unroll 1
    for (int tap=0; tap<9; ++tap){
        u32 hw[4] = {0,0,0,0}, lw[4] = {0,0,0,0};
        #pragma unroll
        for (int e=0;e<16;++e){
            float f = wp[e*9 + tap];
            int w16 = __float2int_rn(f * invS);
            w16 = min(max(w16, -32512), 32512);
            int hi = (w16 + 128) >> 8;            // lo in [-128,127]
            int lo = w16 - (hi << 8);
            hw[e>>2] |= ((u32)(hi & 0xFF)) << ((e&3)*8);
            lw[e>>2] |= ((u32)(lo & 0xFF)) << ((e&3)*8);
        }
        size_t base = (((size_t)(cch*9+tap)*48 + nfg)*2)*1024 + (size_t)lane*16;
        *(uint4*)(wf + base)        = make_uint4(hw[0],hw[1],hw[2],hw[3]);
        *(uint4*)(wf + base + 1024) = make_uint4(lw[0],lw[1],lw[2],lw[3]);
    }
}

// ------- head LIF: x f32 [img][c][pix] -> padded bit rows [img][324][96] ----
__global__ __launch_bounds__(256) void head_bits(
    const float* __restrict__ x, u8* __restrict__ bits)
{
    int gid = blockIdx.x*256 + threadIdx.x;
    int b = gid / 24576, rem = gid - b*24576;
    int cb = rem >> 8, pix = rem & 255;
    int pr = ((pix>>4)+1)*18 + (pix&15) + 1;
    float v[8];
    #pragma unroll
    for (int j=0;j<8;++j) v[j]=0.f;
    #pragma unroll
    for (int t=0;t<4;++t){
        int img = t*16 + b;
        u32 byte = 0;
        #pragma unroll
        for (int j=0;j<8;++j){
            float xv = x[((size_t)img*C_ + cb*8 + j)*NPIX + pix];
            float h = __fadd_rn(v[j], __fmul_rn(__fsub_rn(xv, v[j]), 0.5f));
            u32 s = (h >= 1.0f) ? 1u : 0u;
            v[j] = s ? 0.f : h;
            byte |= s << j;
        }
        bits[(size_t)img*IMGBITS + (size_t)pr*ROWB + cb] = (u8)byte;
    }
}

// ---------------- implicit-GEMM conv3x3 + BN, i8 hi/lo MFMA -----------------
// Block 256 thr (4 waves, 2m x 2n): tile 128 pix x 96 co. Grid 1024:
// cox=bid&7 (XCD-pinned weight slice), mh=(bid>>3)&1, img=bid>>4.
// A: image bit-plane (36 KB LDS) -> per-cch expand to i8 strip (2x14.4 KB,
//    double-buffered, overlaps MFMA) -> ds_read_b128 frags.
// B: i8 hi/lo frag-words streamed from L2, distance-1 double buffer.
template<int EPI>
__global__ __launch_bounds__(256,2) void conv_i8(
    const u8* __restrict__ abits, const u8* __restrict__ wf,
    const float* __restrict__ sb, const float* __restrict__ wmaxp,
    const int* __restrict__ flags,
    float* __restrict__ ybuf, float* __restrict__ out)
{
    __shared__ __align__(16) u8 Ab[324*ROWL];
    __shared__ __align__(16) u8 Aexp[2*AEXP_SZ];
    const int tid = threadIdx.x;
    const int bid = blockIdx.x;
    const int cox = bid & 7, mh = (bid >> 3) & 1, img = bid >> 4;
    const int lane = tid & 63, w = tid >> 6;
    const int wr = w >> 1, wc = w & 1;
    const int lrow = lane & 15, lgrp = lane >> 4;

    if constexpr (EPI == 1){
        if (flags[img] == 0){
            #pragma unroll 1
            for (int i = tid; i < 96*32; i += 256){
                int co = cox*96 + (i >> 5), seg = i & 31;
                float bv = sb[C_ + co];
                f32x4 v; v[0]=bv; v[1]=bv; v[2]=bv; v[3]=bv;
                *(f32x4*)(out + ((size_t)img*C_ + co)*NPIX + mh*128 + seg*4) = v;
            }
            return;
        }
    }

    {   // stage bit-plane
        const u8* src = abits + (size_t)img*IMGBITS;
        #pragma unroll 1
        for (int r = tid; r < 324; r += 256){
            const u8* s = src + r*ROWB;
            u8* d = Ab + r*ROWL;
            #pragma unroll
            for (int j=0;j<6;++j) *(uint4*)(d + j*16) = *(const uint4*)(s + j*16);
        }
    }

    // B pointer: first frag-step, this wave's co block
    const u8* wp = wf + (size_t)((cox*6 + wc*3)*2)*1024 + (size_t)lane*16;
    uint4 B0[6], B1[6];
#define LOADB(BUF) { \
    _Pragma("unroll") \
    for (int j=0;j<6;++j) BUF[j] = *(const uint4*)(wp + (j>>1)*2048 + (j&1)*1024); \
    wp += 98304; }

    LOADB(B0);
    __syncthreads();                       // Ab ready

    // expand channels [CCH*64,+64) of this mh-strip into Aexp[BUFOFF]
#define EXPAND(CCH, BUFOFF) if (tid < 180){ \
    const u8* sp = Ab + (mh*144 + tid)*ROWL + (CCH)*8; \
    u32 blo = *(const u32*)(sp); u32 bhi = *(const u32*)(sp + 4); \
    u8* dp = Aexp + (BUFOFF) + tid*AEXP_STRIDE; \
    *(uint4*)(dp)    = make_uint4(SPREAD(blo&0xF), SPREAD((blo>>4)&0xF), SPREAD((blo>>8)&0xF), SPREAD((blo>>12)&0xF)); \
    *(uint4*)(dp+16) = make_uint4(SPREAD((blo>>16)&0xF), SPREAD((blo>>20)&0xF), SPREAD((blo>>24)&0xF), SPREAD((blo>>28)&0xF)); \
    *(uint4*)(dp+32) = make_uint4(SPREAD(bhi&0xF), SPREAD((bhi>>4)&0xF), SPREAD((bhi>>8)&0xF), SPREAD((bhi>>12)&0xF)); \
    *(uint4*)(dp+48) = make_uint4(SPREAD((bhi>>16)&0xF), SPREAD((bhi>>20)&0xF), SPREAD((bhi>>24)&0xF), SPREAD((bhi>>28)&0xF)); }

    EXPAND(0, 0);
    __syncthreads();

    int rb[4];
    #pragma unroll
    for (int mi=0;mi<4;++mi)
        rb[mi] = (wr*4 + mi + 1)*1440 + (lrow + 1)*AEXP_STRIDE + lgrp*16;

    i32x4 acc_h[4][3], acc_l[4][3];
    #pragma unroll
    for (int mi=0;mi<4;++mi)
        #pragma unroll
        for (int ni=0;ni<3;++ni)
            #pragma unroll
            for (int r=0;r<4;++r){ acc_h[mi][ni][r]=0; acc_l[mi][ni][r]=0; }

#define COMPUTE(BUF, AE, TAP) { \
    const int DT = ((TAP)/3 - 1)*1440 + (((TAP)%3) - 1)*AEXP_STRIDE; \
    i32x4 af[4]; \
    _Pragma("unroll") \
    for (int mi=0;mi<4;++mi) af[mi] = *(const i32x4*)((AE) + rb[mi] + DT); \
    __builtin_amdgcn_s_setprio(1); \
    _Pragma("unroll") \
    for (int mi=0;mi<4;++mi){ \
        _Pragma("unroll") \
        for (int ni=0;ni<3;++ni){ \
            acc_h[mi][ni] = __builtin_amdgcn_mfma_i32_16x16x64_i8(af[mi], as_i4(BUF[ni*2+0]), acc_h[mi][ni], 0,0,0); \
            acc_l[mi][ni] = __builtin_amdgcn_mfma_i32_16x16x64_i8(af[mi], as_i4(BUF[ni*2+1]), acc_l[mi][ni], 0,0,0); \
        } \
    } \
    __builtin_amdgcn_s_setprio(0); }

    // invariant at body entry: X holds current step (tap 0 of CCH); exit: Y holds next
#define CCH_BODY(X, Y, CCH, BUFOFF, DO_EXP) { \
    if (DO_EXP) EXPAND((CCH)+1, (BUFOFF) ^ AEXP_SZ); \
    const u8* Ae = Aexp + (BUFOFF); \
    _Pragma("unroll") \
    for (int tp=0; tp<8; tp+=2){ \
        LOADB(Y); COMPUTE(X, Ae, tp); \
        LOADB(X); COMPUTE(Y, Ae, tp+1); \
    } \
    LOADB(Y); COMPUTE(X, Ae, 8); \
    __syncthreads(); }

    #pragma unroll 1
    for (int c2=0; c2<6; ++c2){
        CCH_BODY(B0, B1, 2*c2,     0,       true);
        CCH_BODY(B1, B0, 2*c2+1,   AEXP_SZ, (c2 < 5));
    }
#undef LOADB
#undef EXPAND
#undef COMPUTE
#undef CCH_BODY

    const float S = (*wmaxp) * (1.0f/32512.0f);
    #pragma unroll
    for (int mi=0;mi<4;++mi){
        const int prow = mh*128 + wr*64 + mi*16 + lgrp*4;
        #pragma unroll
        for (int ni=0;ni<3;++ni){
            const int co = cox*96 + wc*48 + ni*16 + lrow;
            const float sc = sb[co], bi = sb[C_ + co];
            if constexpr (EPI == 0){
                #pragma unroll
                for (int r=0;r<4;++r){
                    float accf = (float)(acc_h[mi][ni][r]*256 + acc_l[mi][ni][r]) * S;
                    ybuf[((size_t)img*NPIX + prow + r)*C_ + co] =
                        __fadd_rn(__fmul_rn(accf, sc), bi);
                }
            } else {
                f32x4 ov;
                #pragma unroll
                for (int r=0;r<4;++r){
                    float accf = (float)(acc_h[mi][ni][r]*256 + acc_l[mi][ni][r]) * S;
                    ov[r] = __fadd_rn(__fmul_rn(accf, sc), bi);
                }
                *(f32x4*)(out + ((size_t)img*C_ + co)*NPIX + prow) = ov;
            }
        }
    }
}

// ---- LIF over ybuf -> u8 plane (for attn) + padded bit rows (for conv) -----
__global__ __launch_bounds__(256) void lif_bits(
    const float* __restrict__ y, u8* __restrict__ su8, u8* __restrict__ bits)
{
    int gid = blockIdx.x*256 + threadIdx.x;
    int b = gid / 24576, rem = gid - b*24576;
    int pix = rem / 96, cb = rem - pix*96;
    int pr = ((pix>>4)+1)*18 + (pix&15) + 1;
    float v[8];
    #pragma unroll
    for (int j=0;j<8;++j) v[j]=0.f;
    #pragma unroll
    for (int t=0;t<4;++t){
        int img = t*16 + b;
        const float* yp = y + ((size_t)img*NPIX + pix)*C_ + cb*8;
        f32x4 y0 = *(const f32x4*)yp;
        f32x4 y1 = *(const f32x4*)(yp + 4);
        u32 byte = 0, w0 = 0, w1 = 0;
        #pragma unroll
        for (int j=0;j<8;++j){
            float yv = (j<4) ? y0[j] : y1[j-4];
            float h = __fadd_rn(v[j], __fmul_rn(__fsub_rn(yv, v[j]), 0.5f));
            u32 s = (h >= 1.0f) ? 1u : 0u;
            v[j] = s ? 0.f : h;
            byte |= s << j;
            if (j<4) w0 |= s << (j*8); else w1 |= s << ((j-4)*8);
        }
        *(uint2*)(su8 + ((size_t)img*NPIX + pix)*C_ + cb*8) = make_uint2(w0,w1);
        bits[(size_t)img*IMGBITS + (size_t)pr*ROWB + cb] = (u8)byte;
    }
}

// ---- o u8 pixel-major -> padded bit rows + per-image any-spike flags -------
__global__ __launch_bounds__(256) void pad_o_bits(
    const u8* __restrict__ o, u8* __restrict__ bits, int* __restrict__ flags)
{
    int gid = blockIdx.x*256 + threadIdx.x;
    int img = gid / 24576, rem = gid - img*24576;
    int pix = rem / 96, cb = rem - pix*96;
    int pr = ((pix>>4)+1)*18 + (pix&15) + 1;
    uint2 r = *(const uint2*)(o + ((size_t)img*NPIX + pix)*C_ + cb*8);
    u32 byte = 0;
    #pragma unroll
    for (int j=0;j<4;++j){
        byte |= ((r.x >> (j*8)) & 1u) << j;
        byte |= ((r.y >> (j*8)) & 1u) << (j+4);
    }
    bits[(size_t)img*IMGBITS + (size_t)pr*ROWB + cb] = (u8)byte;
    if (__any((int)(r.x | r.y)) && (threadIdx.x & 63) == 0)
        atomicOr(&flags[img], 1);
}

// ---------------- attention (verbatim, verified) ----------------------------
__global__ __launch_bounds__(512) void attn_fused(
    const u8* __restrict__ qs, const u8* __restrict__ ks,
    const u8* __restrict__ vs, u8* __restrict__ os)
{
    const int tid = threadIdx.x;
    const int b = blockIdx.x, h = blockIdx.y;
    __shared__ u64 kb[96][4], vb[96][4];
    __shared__ float kvl[96][96];
    const int w = tid >> 6, lane = tid & 63;
    const int ng = w & 3, n_build = ng*64 + lane;
    const int n = tid & 255, eh = tid >> 8;
    float vmem[48];
    #pragma unroll
    for (int e=0;e<48;++e) vmem[e]=0.f;

    for (int t=0;t<4;++t){
        const int img = t*16 + b;
        const size_t rbase = ((size_t)img*NPIX)*C_ + (size_t)h*96;
        {
            const u8* src = (w < 4 ? ks : vs) + rbase + (size_t)n_build*C_;
            uint4 r[6];
            #pragma unroll
            for (int j=0;j<6;++j) r[j] = ((const uint4*)src)[j];
            u32 wd[24];
            #pragma unroll
            for (int j=0;j<6;++j){ wd[4*j]=r[j].x; wd[4*j+1]=r[j].y; wd[4*j+2]=r[j].z; wd[4*j+3]=r[j].w; }
            u64 (*dst)[4] = (w < 4) ? kb : vb;
            #pragma unroll 1
            for (int d=0; d<96; ++d){
                u32 byte = (wd[d>>2] >> ((d&3)*8)) & 0xFFu;
                u64 m = __ballot((int)byte);
                if (lane == 0) dst[d][ng] = m;
            }
        }
        __syncthreads();
        for (int i = tid; i < 96*96; i += 512){
            int d = i / 96, e = i - d*96;
            int s = 0;
            #pragma unroll
            for (int g=0; g<4; ++g) s += __popcll(kb[d][g] & vb[e][g]);
            kvl[d][e] = (float)s;
        }
        __syncthreads();
        {
            const u8* qsrc = qs + rbase + (size_t)n*C_;
            uint4 r[6];
            #pragma unroll
            for (int j=0;j<6;++j) r[j] = ((const uint4*)qsrc)[j];
            u32 qw[24];
            #pragma unroll
            for (int j=0;j<6;++j){ qw[4*j]=r[j].x; qw[4*j+1]=r[j].y; qw[4*j+2]=r[j].z; qw[4*j+3]=r[j].w; }
            float val[48];
            #pragma unroll
            for (int e=0;e<48;++e) val[e]=0.f;
            #pragma unroll 1
            for (int d=0; d<96; ++d){
                u32 qb = (qw[d>>2] >> ((d&3)*8)) & 0xFFu;
                if (__any((int)qb)){
                    float qf = (float)qb;
                    #pragma unroll
                    for (int e=0;e<48;++e) val[e] += qf * kvl[d][eh*48+e];
                }
            }
            u32 ow[12];
            #pragma unroll
            for (int e=0;e<48;++e){
                float o = val[e]*0.125f;
                float hh = __fadd_rn(vmem[e], __fmul_rn(__fsub_rn(o, vmem[e]), 0.5f));
                u8 s = (hh >= 0.5f) ? 1 : 0;
                vmem[e] = s ? 0.f : hh;
                if ((e&3)==0) ow[e>>2] = (u32)s; else ow[e>>2] |= ((u32)s) << ((e&3)*8);
            }
            uint4* od = (uint4*)(os + rbase + (size_t)n*C_ + eh*48);
            od[0] = make_uint4(ow[0],ow[1],ow[2],ow[3]);
            od[1] = make_uint4(ow[4],ow[5],ow[6],ow[7]);
            od[2] = make_uint4(ow[8],ow[9],ow[10],ow[11]);
        }
        __syncthreads();
    }
}

// ---------------------------------------------------------------------------
extern "C" void kernel_launch(void* const* d_in, const int* in_sizes, int n_in,
                              void* d_out, int out_size, void* d_ws, size_t ws_size,
                              hipStream_t stream)
{
    u8* ws = (u8*)d_ws;
    u8* wfrag   = ws + OFF_WFRAG;
    float* ybuf = (float*)(ws + OFF_YBUF);
    u8* q_u8 = ws + OFF_QU8;
    u8* k_u8 = ws + OFF_KU8;
    u8* v_u8 = ws + OFF_VU8;
    u8* o_u8 = ws + OFF_OU8;
    u8* xs_b = ws + OFF_BITS;
    u8* q_b  = ws + OFF_BITS + 1*BITSZ;
    u8* k_b  = ws + OFF_BITS + 2*BITSZ;
    u8* v_b  = ws + OFF_BITS + 3*BITSZ;
    u8* o_b  = ws + OFF_BITS + 4*BITSZ;
    float* sbt = (float*)(ws + OFF_SBT);
    int* flags = (int*)(ws + OFF_FLAGS);
    float* wmaxb = (float*)(ws + OFF_WMAX);
    float* outp = (float*)d_out;
    const int WN = 9*C_*C_;   // 5,308,416

    hipMemsetAsync(ws + OFF_BITS, 0, 5*BITSZ, stream);
    hipMemsetAsync(ws + OFF_FLAGS, 0, 512, stream);   // flags + wmax slots

    for (int s=0;s<4;++s)
        bn_prep<<<3,256,0,stream>>>((const float*)d_in[2+5*s], (const float*)d_in[3+5*s],
                                    (const float*)d_in[4+5*s], (const float*)d_in[5+5*s],
                                    sbt + s*1536);
    head_bits<<<1536,256,0,stream>>>((const float*)d_in[0], xs_b);

    u8* u8p[3]  = {q_u8, k_u8, v_u8};
    u8* bitp[3] = {q_b, k_b, v_b};
    for (int s=0;s<3;++s){
        wmax_k<<<512,256,0,stream>>>((const float*)d_in[1+5*s], WN, wmaxb + s);
        wprep<<<144,256,0,stream>>>((const float*)d_in[1+5*s], wmaxb + s, wfrag);
        conv_i8<0><<<1024,256,0,stream>>>(xs_b, wfrag, sbt + s*1536, wmaxb + s,
                                          nullptr, ybuf, nullptr);
        lif_bits<<<1536,256,0,stream>>>(ybuf, u8p[s], bitp[s]);
    }
    attn_fused<<<dim3(16,8),512,0,stream>>>(q_u8, k_u8, v_u8, o_u8);
    pad_o_bits<<<6144,256,0,stream>>>(o_u8, o_b, flags);
    wmax_k<<<512,256,0,stream>>>((const float*)d_in[16], WN, wmaxb + 3);
    wprep<<<144,256,0,stream>>>((const float*)d_in[16], wmaxb + 3, wfrag);
    conv_i8<1><<<1024,256,0,stream>>>(o_b, wfrag, sbt + 4608, wmaxb + 3,
                                      flags, nullptr, outp);
}

// Round 6
// 600.747 us; speedup vs baseline: 54.3447x; 1.1373x over previous
//
#include <hip/hip_runtime.h>

typedef __attribute__((ext_vector_type(4))) int   i32x4;
typedef __attribute__((ext_vector_type(4))) float f32x4;
typedef unsigned int u32;
typedef unsigned long long u64;
typedef unsigned char u8;
typedef unsigned short u16;

#define C_ 768
#define NPIX 256
#define PLANE (16*C_*NPIX)
#define ROWB 96            // bytes per padded bit-row (one pixel's 768 bits)
#define IMGBITS (324*ROWB) // 31104 B per image (18x18 padded pixels)
// Aexp layout: [pr 10][lgrp 4][pc 18][16B]; strides chosen odd*4words mod 32 banks
#define GS   304           // lgrp stride (76 words, %32 = 12)
#define PRS  1232          // pixel-row stride = 4*GS + 16 (308 words, %32 = 20)
#define AEXP_SZ 12320      // 10 * PRS

// workspace map
#define OFF_WFRAG 0ull            // 10,616,832 (9tap x 768co x 768c, i8 hi+lo, frag order)
#define OFF_YBUF  10616832ull     // 50,331,648 f32
#define OFF_QU8   60948480ull     // 12,582,912 each
#define OFF_KU8   73531392ull
#define OFF_VU8   86114304ull
#define OFF_OU8   98697216ull
#define OFF_BITS  111280128ull    // 5 x 1,990,656
#define BITSZ     1990656ull
#define OFF_SBT   121233408ull    // 4 x 1536 f32
#define OFF_FLAGS 121257984ull    // 64 int
#define OFF_WMAX  121258240ull    // 4 f32

__device__ __forceinline__ i32x4 as_i4(uint4 v){ union{uint4 u; i32x4 s;} c; c.u=v; return c.s; }
#define SPREAD(NIB) ((u32)__mul24((int)(NIB), 0x204081) & 0x01010101u)

// ---------------- BN affine x4: [s][0..767]=scale, [s][768..1535]=bias ------
__global__ __launch_bounds__(256) void bn_prep4(
    const float* __restrict__ g0, const float* __restrict__ b0,
    const float* __restrict__ m0, const float* __restrict__ v0,
    const float* __restrict__ g1, const float* __restrict__ b1,
    const float* __restrict__ m1, const float* __restrict__ v1,
    const float* __restrict__ g2, const float* __restrict__ b2,
    const float* __restrict__ m2, const float* __restrict__ v2,
    const float* __restrict__ g3, const float* __restrict__ b3,
    const float* __restrict__ m3, const float* __restrict__ v3,
    float* __restrict__ out)
{
    int s = blockIdx.y;
    const float* g  = s==0?g0:s==1?g1:s==2?g2:g3;
    const float* be = s==0?b0:s==1?b1:s==2?b2:b3;
    const float* m  = s==0?m0:s==1?m1:s==2?m2:m3;
    const float* va = s==0?v0:s==1?v1:s==2?v2:v3;
    int i = blockIdx.x*256 + threadIdx.x;
    if (i < C_){
        float sc = g[i] / sqrtf(va[i] + 1e-5f);
        out[s*1536 + i] = sc;
        out[s*1536 + C_ + i] = be[i] - m[i]*sc;
    }
}

// ---------------- max|w| reduction x4 (dynamic i16 scales) ------------------
__global__ __launch_bounds__(256) void wmax4(
    const float* __restrict__ w0, const float* __restrict__ w1,
    const float* __restrict__ w2, const float* __restrict__ w3,
    float* __restrict__ out)
{
    int s = blockIdx.y;
    const float* w = s==0?w0:s==1?w1:s==2?w2:w3;
    const int n4 = 9*C_*C_/4;                    // 1,327,104 float4s
    float m = 0.f;
    for (int i = blockIdx.x*256 + threadIdx.x; i < n4; i += 65536){
        f32x4 v = *(const f32x4*)(w + (size_t)i*4);
        m = fmaxf(m, fmaxf(fmaxf(fabsf(v[0]), fabsf(v[1])),
                           fmaxf(fabsf(v[2]), fabsf(v[3]))));
    }
    #pragma unroll
    for (int off = 32; off >= 1; off >>= 1)
        m = fmaxf(m, __shfl_xor(m, off));
    if ((threadIdx.x & 63) == 0)
        atomicMax((int*)(out + s), __float_as_int(m));
}

// ---- weight prep: f32 [co][c][9] -> i8 hi/lo fragment-ordered --------------
__global__ __launch_bounds__(256) void wprep(
    const float* __restrict__ w, const float* __restrict__ wmaxp,
    u8* __restrict__ wf)
{
    int gid = blockIdx.x*256 + threadIdx.x;     // 36864 = 768co x 48 c16
    int co = gid / 48, c16 = gid - co*48;
    float mw = *wmaxp;
    float invS = (mw > 0.f) ? (32512.0f / mw) : 0.f;
    int cch = c16 >> 2;
    int lane = (co & 15) | ((c16 & 3) << 4);
    int nfg = co >> 4;
    const float* wp = w + (size_t)co*6912 + (size_t)c16*144;   // 16 c x 9 taps
    #pragma unroll 1
    for (int tap=0; tap<9; ++tap){
        u32 hw[4] = {0,0,0,0}, lw[4] = {0,0,0,0};
        #pragma unroll
        for (int e=0;e<16;++e){
            float f = wp[e*9 + tap];
            int w16 = __float2int_rn(f * invS);
            w16 = min(max(w16, -32512), 32512);
            int hi = (w16 + 128) >> 8;            // lo in [-128,127]
            int lo = w16 - (hi << 8);
            hw[e>>2] |= ((u32)(hi & 0xFF)) << ((e&3)*8);
            lw[e>>2] |= ((u32)(lo & 0xFF)) << ((e&3)*8);
        }
        size_t base = (((size_t)(cch*9+tap)*48 + nfg)*2)*1024 + (size_t)lane*16;
        *(uint4*)(wf + base)        = make_uint4(hw[0],hw[1],hw[2],hw[3]);
        *(uint4*)(wf + base + 1024) = make_uint4(lw[0],lw[1],lw[2],lw[3]);
    }
}

// ------- head LIF: x f32 [img][c][pix] -> padded bit rows [img][324][96] ----
__global__ __launch_bounds__(256) void head_bits(
    const float* __restrict__ x, u8* __restrict__ bits)
{
    int gid = blockIdx.x*256 + threadIdx.x;
    int b = gid / 24576, rem = gid - b*24576;
    int cb = rem >> 8, pix = rem & 255;
    int pr = ((pix>>4)+1)*18 + (pix&15) + 1;
    float v[8];
    #pragma unroll
    for (int j=0;j<8;++j) v[j]=0.f;
    #pragma unroll
    for (int t=0;t<4;++t){
        int img = t*16 + b;
        u32 byte = 0;
        #pragma unroll
        for (int j=0;j<8;++j){
            float xv = x[((size_t)img*C_ + cb*8 + j)*NPIX + pix];
            float h = __fadd_rn(v[j], __fmul_rn(__fsub_rn(xv, v[j]), 0.5f));
            u32 s = (h >= 1.0f) ? 1u : 0u;
            v[j] = s ? 0.f : h;
            byte |= s << j;
        }
        bits[(size_t)img*IMGBITS + (size_t)pr*ROWB + cb] = (u8)byte;
    }
}

// ---------------- implicit-GEMM conv3x3 + BN, i8 hi/lo MFMA -----------------
// Block 256 thr (4 waves, 2m x 2n): tile 128 pix x 96 co. Grid 1024:
// cox=bid&7 (XCD-pinned weight slice), mh=(bid>>3)&1, img=bid>>4.
// A: bits read straight from global (L2-hot), expanded per 64-chan chunk into
//    a conflict-free LDS tile (2 x 12.3 KB double buffer). Bit-loads issued
//    one chunk early; expansion lands after the chunk's compute.
// B: i8 hi/lo frag-words streamed from L2, distance-2 triple-buffer ring.
template<int EPI>
__global__ __launch_bounds__(256,2) void conv_i8(
    const u8* __restrict__ abits, const u8* __restrict__ wf,
    const float* __restrict__ sb, const float* __restrict__ wmaxp,
    const int* __restrict__ flags,
    float* __restrict__ ybuf, float* __restrict__ out)
{
    __shared__ __align__(16) u8 Aexp[2*AEXP_SZ];
    const int tid = threadIdx.x;
    const int bid = blockIdx.x;
    const int cox = bid & 7, mh = (bid >> 3) & 1, img = bid >> 4;
    const int lane = tid & 63, w = tid >> 6;
    const int wr = w >> 1, wc = w & 1;
    const int lrow = lane & 15, lgrp = lane >> 4;

    if constexpr (EPI == 1){
        if (flags[img] == 0){
            #pragma unroll 1
            for (int i = tid; i < 96*32; i += 256){
                int co = cox*96 + (i >> 5), seg = i & 31;
                float bv = sb[C_ + co];
                f32x4 v; v[0]=bv; v[1]=bv; v[2]=bv; v[3]=bv;
                *(f32x4*)(out + ((size_t)img*C_ + co)*NPIX + mh*128 + seg*4) = v;
            }
            return;
        }
    }

    // EXPAND geometry: strip pixel index tid (<180) = pr*18 + pc
    const int erow = (tid < 180) ? tid : 179;
    const int epr = erow / 18, epc = erow - epr*18;
    u8* edst = Aexp + epr*PRS + epc*16;
    const u8* bsrc = abits + (size_t)img*IMGBITS + (size_t)(mh*144)*ROWB;

#define EXPW(BW, BOFF) if (tid < 180){ \
    u8* dp = edst + (BOFF); \
    u32 lo_ = (u32)(BW), hi_ = (u32)((BW)>>32); \
    *(uint4*)(dp       ) = make_uint4(SPREAD(lo_&0xF), SPREAD((lo_>>4)&0xF), SPREAD((lo_>>8)&0xF), SPREAD((lo_>>12)&0xF)); \
    *(uint4*)(dp + GS  ) = make_uint4(SPREAD((lo_>>16)&0xF), SPREAD((lo_>>20)&0xF), SPREAD((lo_>>24)&0xF), SPREAD((lo_>>28)&0xF)); \
    *(uint4*)(dp + 2*GS) = make_uint4(SPREAD(hi_&0xF), SPREAD((hi_>>4)&0xF), SPREAD((hi_>>8)&0xF), SPREAD((hi_>>12)&0xF)); \
    *(uint4*)(dp + 3*GS) = make_uint4(SPREAD((hi_>>16)&0xF), SPREAD((hi_>>20)&0xF), SPREAD((hi_>>24)&0xF), SPREAD((hi_>>28)&0xF)); }

    // B streaming: distance-2 ring
    const u8* wp = wf + (size_t)((cox*6 + wc*3)*2)*1024 + (size_t)lane*16;
    uint4 R0[6], R1[6], R2[6];
#define LOADB(BUF) { \
    _Pragma("unroll") \
    for (int j=0;j<6;++j) BUF[j] = *(const uint4*)(wp + (j>>1)*2048 + (j&1)*1024); \
    wp += 98304; }

    int rb[4];
    #pragma unroll
    for (int mi=0;mi<4;++mi)
        rb[mi] = (wr*4 + mi + 1)*PRS + lgrp*GS + (lrow+1)*16;

    i32x4 acc_h[4][3], acc_l[4][3];
    #pragma unroll
    for (int mi=0;mi<4;++mi)
        #pragma unroll
        for (int ni=0;ni<3;++ni)
            #pragma unroll
            for (int r=0;r<4;++r){ acc_h[mi][ni][r]=0; acc_l[mi][ni][r]=0; }

#define COMPUTE(BUF, AE, TAP) { \
    const int DT = ((TAP)/3 - 1)*PRS + (((TAP)%3) - 1)*16; \
    i32x4 af[4]; \
    _Pragma("unroll") \
    for (int mi=0;mi<4;++mi) af[mi] = *(const i32x4*)((AE) + rb[mi] + DT); \
    __builtin_amdgcn_s_setprio(1); \
    _Pragma("unroll") \
    for (int mi=0;mi<4;++mi){ \
        _Pragma("unroll") \
        for (int ni=0;ni<3;++ni){ \
            acc_h[mi][ni] = __builtin_amdgcn_mfma_i32_16x16x64_i8(af[mi], as_i4(BUF[ni*2+0]), acc_h[mi][ni], 0,0,0); \
            acc_l[mi][ni] = __builtin_amdgcn_mfma_i32_16x16x64_i8(af[mi], as_i4(BUF[ni*2+1]), acc_l[mi][ni], 0,0,0); \
        } \
    } \
    __builtin_amdgcn_s_setprio(0); }

    // body: entry invariant R0=tap0, R1=tap1 of CCH; exit same for CCH+1
#define BODY(CCH, BOFF) { \
    u64 bwn = 0; \
    if ((CCH) < 11) bwn = *(const u64*)(bsrc + erow*ROWB + ((CCH)+1)*8); \
    const u8* Ae = Aexp + (BOFF); \
    LOADB(R2); COMPUTE(R0, Ae, 0); \
    LOADB(R0); COMPUTE(R1, Ae, 1); \
    LOADB(R1); COMPUTE(R2, Ae, 2); \
    LOADB(R2); COMPUTE(R0, Ae, 3); \
    LOADB(R0); COMPUTE(R1, Ae, 4); \
    LOADB(R1); COMPUTE(R2, Ae, 5); \
    LOADB(R2); COMPUTE(R0, Ae, 6); \
    LOADB(R0); COMPUTE(R1, Ae, 7); \
    LOADB(R1); COMPUTE(R2, Ae, 8); \
    if ((CCH) < 11) EXPW(bwn, (BOFF) ^ AEXP_SZ); \
    __syncthreads(); }

    // prologue: B ring primed with tap0,tap1; expand chunk 0
    LOADB(R0); LOADB(R1);
    {
        u64 bw0 = *(const u64*)(bsrc + erow*ROWB);
        EXPW(bw0, 0);
    }
    __syncthreads();

    #pragma unroll 1
    for (int c2=0; c2<6; ++c2){
        BODY(2*c2,   0);
        BODY(2*c2+1, AEXP_SZ);
    }
#undef LOADB
#undef EXPW
#undef COMPUTE
#undef BODY

    const float S = (*wmaxp) * (1.0f/32512.0f);
    #pragma unroll
    for (int mi=0;mi<4;++mi){
        const int prow = mh*128 + wr*64 + mi*16 + lgrp*4;
        #pragma unroll
        for (int ni=0;ni<3;++ni){
            const int co = cox*96 + wc*48 + ni*16 + lrow;
            const float sc = sb[co], bi = sb[C_ + co];
            if constexpr (EPI == 0){
                #pragma unroll
                for (int r=0;r<4;++r){
                    float accf = (float)(acc_h[mi][ni][r]*256 + acc_l[mi][ni][r]) * S;
                    ybuf[((size_t)img*NPIX + prow + r)*C_ + co] =
                        __fadd_rn(__fmul_rn(accf, sc), bi);
                }
            } else {
                f32x4 ov;
                #pragma unroll
                for (int r=0;r<4;++r){
                    float accf = (float)(acc_h[mi][ni][r]*256 + acc_l[mi][ni][r]) * S;
                    ov[r] = __fadd_rn(__fmul_rn(accf, sc), bi);
                }
                *(f32x4*)(out + ((size_t)img*C_ + co)*NPIX + prow) = ov;
            }
        }
    }
}

// ---- LIF over ybuf -> u8 plane (for attn) + padded bit rows (for conv) -----
__global__ __launch_bounds__(256) void lif_bits(
    const float* __restrict__ y, u8* __restrict__ su8, u8* __restrict__ bits)
{
    int gid = blockIdx.x*256 + threadIdx.x;
    int b = gid / 24576, rem = gid - b*24576;
    int pix = rem / 96, cb = rem - pix*96;
    int pr = ((pix>>4)+1)*18 + (pix&15) + 1;
    float v[8];
    #pragma unroll
    for (int j=0;j<8;++j) v[j]=0.f;
    #pragma unroll
    for (int t=0;t<4;++t){
        int img = t*16 + b;
        const float* yp = y + ((size_t)img*NPIX + pix)*C_ + cb*8;
        f32x4 y0 = *(const f32x4*)yp;
        f32x4 y1 = *(const f32x4*)(yp + 4);
        u32 byte = 0, w0 = 0, w1 = 0;
        #pragma unroll
        for (int j=0;j<8;++j){
            float yv = (j<4) ? y0[j] : y1[j-4];
            float h = __fadd_rn(v[j], __fmul_rn(__fsub_rn(yv, v[j]), 0.5f));
            u32 s = (h >= 1.0f) ? 1u : 0u;
            v[j] = s ? 0.f : h;
            byte |= s << j;
            if (j<4) w0 |= s << (j*8); else w1 |= s << ((j-4)*8);
        }
        *(uint2*)(su8 + ((size_t)img*NPIX + pix)*C_ + cb*8) = make_uint2(w0,w1);
        bits[(size_t)img*IMGBITS + (size_t)pr*ROWB + cb] = (u8)byte;
    }
}

// ---- o u8 pixel-major -> padded bit rows + per-image any-spike flags -------
__global__ __launch_bounds__(256) void pad_o_bits(
    const u8* __restrict__ o, u8* __restrict__ bits, int* __restrict__ flags)
{
    int gid = blockIdx.x*256 + threadIdx.x;
    int img = gid / 24576, rem = gid - img*24576;
    int pix = rem / 96, cb = rem - pix*96;
    int pr = ((pix>>4)+1)*18 + (pix&15) + 1;
    uint2 r = *(const uint2*)(o + ((size_t)img*NPIX + pix)*C_ + cb*8);
    u32 byte = 0;
    #pragma unroll
    for (int j=0;j<4;++j){
        byte |= ((r.x >> (j*8)) & 1u) << j;
        byte |= ((r.y >> (j*8)) & 1u) << (j+4);
    }
    bits[(size_t)img*IMGBITS + (size_t)pr*ROWB + cb] = (u8)byte;
    if (__any((int)(r.x | r.y)) && (threadIdx.x & 63) == 0)
        atomicOr(&flags[img], 1);
}

// ---------------- attention (verbatim, verified) ----------------------------
__global__ __launch_bounds__(512) void attn_fused(
    const u8* __restrict__ qs, const u8* __restrict__ ks,
    const u8* __restrict__ vs, u8* __restrict__ os)
{
    const int tid = threadIdx.x;
    const int b = blockIdx.x, h = blockIdx.y;
    __shared__ u64 kb[96][4], vb[96][4];
    __shared__ float kvl[96][96];
    const int w = tid >> 6, lane = tid & 63;
    const int ng = w & 3, n_build = ng*64 + lane;
    const int n = tid & 255, eh = tid >> 8;
    float vmem[48];
    #pragma unroll
    for (int e=0;e<48;++e) vmem[e]=0.f;

    for (int t=0;t<4;++t){
        const int img = t*16 + b;
        const size_t rbase = ((size_t)img*NPIX)*C_ + (size_t)h*96;
        {
            const u8* src = (w < 4 ? ks : vs) + rbase + (size_t)n_build*C_;
            uint4 r[6];
            #pragma unroll
            for (int j=0;j<6;++j) r[j] = ((const uint4*)src)[j];
            u32 wd[24];
            #pragma unroll
            for (int j=0;j<6;++j){ wd[4*j]=r[j].x; wd[4*j+1]=r[j].y; wd[4*j+2]=r[j].z; wd[4*j+3]=r[j].w; }
            u64 (*dst)[4] = (w < 4) ? kb : vb;
            #pragma unroll 1
            for (int d=0; d<96; ++d){
                u32 byte = (wd[d>>2] >> ((d&3)*8)) & 0xFFu;
                u64 m = __ballot((int)byte);
                if (lane == 0) dst[d][ng] = m;
            }
        }
        __syncthreads();
        for (int i = tid; i < 96*96; i += 512){
            int d = i / 96, e = i - d*96;
            int s = 0;
            #pragma unroll
            for (int g=0; g<4; ++g) s += __popcll(kb[d][g] & vb[e][g]);
            kvl[d][e] = (float)s;
        }
        __syncthreads();
        {
            const u8* qsrc = qs + rbase + (size_t)n*C_;
            uint4 r[6];
            #pragma unroll
            for (int j=0;j<6;++j) r[j] = ((const uint4*)qsrc)[j];
            u32 qw[24];
            #pragma unroll
            for (int j=0;j<6;++j){ qw[4*j]=r[j].x; qw[4*j+1]=r[j].y; qw[4*j+2]=r[j].z; qw[4*j+3]=r[j].w; }
            float val[48];
            #pragma unroll
            for (int e=0;e<48;++e) val[e]=0.f;
            #pragma unroll 1
            for (int d=0; d<96; ++d){
                u32 qb = (qw[d>>2] >> ((d&3)*8)) & 0xFFu;
                if (__any((int)qb)){
                    float qf = (float)qb;
                    #pragma unroll
                    for (int e=0;e<48;++e) val[e] += qf * kvl[d][eh*48+e];
                }
            }
            u32 ow[12];
            #pragma unroll
            for (int e=0;e<48;++e){
                float o = val[e]*0.125f;
                float hh = __fadd_rn(vmem[e], __fmul_rn(__fsub_rn(o, vmem[e]), 0.5f));
                u8 s = (hh >= 0.5f) ? 1 : 0;
                vmem[e] = s ? 0.f : hh;
                if ((e&3)==0) ow[e>>2] = (u32)s; else ow[e>>2] |= ((u32)s) << ((e&3)*8);
            }
            uint4* od = (uint4*)(os + rbase + (size_t)n*C_ + eh*48);
            od[0] = make_uint4(ow[0],ow[1],ow[2],ow[3]);
            od[1] = make_uint4(ow[4],ow[5],ow[6],ow[7]);
            od[2] = make_uint4(ow[8],ow[9],ow[10],ow[11]);
        }
        __syncthreads();
    }
}

// ---------------------------------------------------------------------------
extern "C" void kernel_launch(void* const* d_in, const int* in_sizes, int n_in,
                              void* d_out, int out_size, void* d_ws, size_t ws_size,
                              hipStream_t stream)
{
    u8* ws = (u8*)d_ws;
    u8* wfrag   = ws + OFF_WFRAG;
    float* ybuf = (float*)(ws + OFF_YBUF);
    u8* q_u8 = ws + OFF_QU8;
    u8* k_u8 = ws + OFF_KU8;
    u8* v_u8 = ws + OFF_VU8;
    u8* o_u8 = ws + OFF_OU8;
    u8* xs_b = ws + OFF_BITS;
    u8* q_b  = ws + OFF_BITS + 1*BITSZ;
    u8* k_b  = ws + OFF_BITS + 2*BITSZ;
    u8* v_b  = ws + OFF_BITS + 3*BITSZ;
    u8* o_b  = ws + OFF_BITS + 4*BITSZ;
    float* sbt = (float*)(ws + OFF_SBT);
    int* flags = (int*)(ws + OFF_FLAGS);
    float* wmaxb = (float*)(ws + OFF_WMAX);
    float* outp = (float*)d_out;

    hipMemsetAsync(ws + OFF_BITS, 0, 5*BITSZ, stream);
    hipMemsetAsync(ws + OFF_FLAGS, 0, 512, stream);   // flags + wmax slots

    bn_prep4<<<dim3(3,4),256,0,stream>>>(
        (const float*)d_in[2],  (const float*)d_in[3],  (const float*)d_in[4],  (const float*)d_in[5],
        (const float*)d_in[7],  (const float*)d_in[8],  (const float*)d_in[9],  (const float*)d_in[10],
        (const float*)d_in[12], (const float*)d_in[13], (const float*)d_in[14], (const float*)d_in[15],
        (const float*)d_in[17], (const float*)d_in[18], (const float*)d_in[19], (const float*)d_in[20],
        sbt);
    wmax4<<<dim3(256,4),256,0,stream>>>(
        (const float*)d_in[1], (const float*)d_in[6],
        (const float*)d_in[11], (const float*)d_in[16], wmaxb);
    head_bits<<<1536,256,0,stream>>>((const float*)d_in[0], xs_b);

    u8* u8p[3]  = {q_u8, k_u8, v_u8};
    u8* bitp[3] = {q_b, k_b, v_b};
    for (int s=0;s<3;++s){
        wprep<<<144,256,0,stream>>>((const float*)d_in[1+5*s], wmaxb + s, wfrag);
        conv_i8<0><<<1024,256,0,stream>>>(xs_b, wfrag, sbt + s*1536, wmaxb + s,
                                          nullptr, ybuf, nullptr);
        lif_bits<<<1536,256,0,stream>>>(ybuf, u8p[s], bitp[s]);
    }
    attn_fused<<<dim3(16,8),512,0,stream>>>(q_u8, k_u8, v_u8, o_u8);
    pad_o_bits<<<6144,256,0,stream>>>(o_u8, o_b, flags);
    wprep<<<144,256,0,stream>>>((const float*)d_in[16], wmaxb + 3, wfrag);
    conv_i8<1><<<1024,256,0,stream>>>(o_b, wfrag, sbt + 4608, wmaxb + 3,
                                      flags, nullptr, outp);
}